// Round 7
// baseline (399.633 us; speedup 1.0000x reference)
//
#include <hip/hip_runtime.h>

typedef float        f32x4 __attribute__((ext_vector_type(4)));
typedef short        s16x8 __attribute__((ext_vector_type(8)));
typedef unsigned int u32x4 __attribute__((ext_vector_type(4)));

#define EPS_LN2      0.0017328679513998632f   /* eps*ln2, eps = 0.0025 */
#define INV_EPS_LN2  577.0780163555852f       /* 1/(eps*ln2) */
#define LOG2_36      5.169925001442312f

__device__ __forceinline__ short f2bf(float x) {
  unsigned int u; __builtin_memcpy(&u, &x, 4);
  u = (u + 0x7FFFu + ((u >> 16) & 1u)) >> 16;   // RNE
  return (short)u;
}

__device__ __forceinline__ unsigned short f2h(float x) {
  return __builtin_bit_cast(unsigned short, (_Float16)x);
}
__device__ __forceinline__ float h2f(unsigned short h) {
  return (float)__builtin_bit_cast(_Float16, h);
}

#define GLOAD16(g, l) __builtin_amdgcn_global_load_lds( \
    (const __attribute__((address_space(1))) void*)(g), \
    (__attribute__((address_space(3))) void*)(l), 16, 0, 0)

// ---------------------------------------------------------------------------
// k_prep: blocks [0,88) pack W_rt/W_ri into MFMA B-frag order (bf16);
// blocks [88,456) K-split GEMM writing per-job slices pre[23][128][200].
// ---------------------------------------------------------------------------
__global__ __launch_bounds__(256) void k_prep(
    const float* __restrict__ W_rt, const float* __restrict__ W_ri,
    short* __restrict__ frt, short* __restrict__ fri,
    const float* __restrict__ txt, const float* __restrict__ img,
    const float* __restrict__ social,
    const float* __restrict__ W_stat, const float* __restrict__ b_stat,
    const float* __restrict__ W_gt, const float* __restrict__ W_gi,
    float* __restrict__ pre) {
  __shared__ float sA[32][128];
  int bid = blockIdx.x;
  if (bid < 88) {
    int slot = bid * 256 + threadIdx.x;   // 22528 total
    const float* W; short* dst; int f;
    if (slot < 6144) { W = W_rt; dst = frt; f = slot; }
    else             { W = W_ri; dst = fri; f = slot - 6144; }
    int k32 = f >> 8, rem = f & 255, ct = rem >> 6, l = rem & 63;
    int col = ct * 16 + (l & 15);
    int k0  = k32 * 32 + (l >> 4) * 8;
    s16x8 p;
#pragma unroll
    for (int c = 0; c < 8; ++c) {
      float v = (col < 50) ? W[(k0 + c) * 50 + col] : 0.f;
      p[c] = f2bf(v);
    }
    *(s16x8*)(dst + (long)f * 8) = p;
    return;
  }
  int gb = bid - 88;
  int job = gb >> 4, rb = (gb >> 2) & 3, cb = gb & 3;
  int t = threadIdx.x, r0 = rb * 32;
  const float* W; int k0, klen;
  if (job < 6)       { k0 = job * 128;       klen = 128; W = W_gt; }
  else if (job == 6) { k0 = 0;               klen = 100; W = W_gt + 768 * 200; }
  else               { k0 = (job - 7) * 128; klen = 128; W = W_gi; }
  if (job == 6) {
    for (int idx = t; idx < 4096; idx += 256) {
      int r = idx >> 7, k = idx & 127;
      float v = 0.f;
      if (k < 100) {
        v = b_stat[k];
#pragma unroll
        for (int u = 0; u < 10; ++u) v += social[(r0 + r) * 10 + u] * W_stat[u * 100 + k];
        v = fmaxf(v, 0.f);
      }
      sA[r][k] = v;
    }
  } else {
    const float* A = (job < 6) ? txt : img;
    int K_A = (job < 6) ? 768 : 2048;
    for (int idx = t; idx < 4096; idx += 256) {
      int r = idx >> 7, k = idx & 127;
      sA[r][k] = A[(r0 + r) * K_A + k0 + k];
    }
  }
  __syncthreads();
  int c = cb * 64 + (t & 63), rg = t >> 6;
  if (c < 200) {
    float acc[8];
#pragma unroll
    for (int i = 0; i < 8; ++i) acc[i] = 0.f;
    for (int k4 = 0; k4 < klen; k4 += 4) {
      float w0 = W[(k0 + k4    ) * 200 + c];
      float w1 = W[(k0 + k4 + 1) * 200 + c];
      float w2 = W[(k0 + k4 + 2) * 200 + c];
      float w3 = W[(k0 + k4 + 3) * 200 + c];
#pragma unroll
      for (int i = 0; i < 8; ++i) {
        f32x4 a = *(const f32x4*)&sA[rg * 8 + i][k4];
        acc[i] += a[0]*w0 + a[1]*w1 + a[2]*w2 + a[3]*w3;
      }
    }
    float* dst = pre + (long)job * 25600;
#pragma unroll
    for (int i = 0; i < 8; ++i)
      dst[(r0 + rg * 8 + i) * 200 + c] = acc[i];
  }
}

// ---------------------------------------------------------------------------
// Projection GEMM: wave-private 3-stage LDS ring via global_load_lds
// (zero VGPR cost, counted vmcnt(12) steady-state -> ~2 stages always in
// flight, NO barriers in the loop). A-source addresses pre-swizzled on the
// GLOBAL side so the linear LDS dest reads back bank-uniform.
// One block = 32 rows x 2 row-groups x 2 K-halves (4 waves), one end-reduce.
// 72KB LDS -> 2 blocks/CU (8 waves). out[M][64] = relu(A[M][K] @ W + bias).
// ---------------------------------------------------------------------------
template<int K32>
__device__ __forceinline__ void proj_body(const float* __restrict__ A,
                                          const short* __restrict__ Bf,
                                          const float* __restrict__ bias,
                                          float* __restrict__ out, int bid,
                                          char* smem) {
  constexpr int KH = K32 / 2;               // k32 steps per wave
  int wave = threadIdx.x >> 6, lane = threadIdx.x & 63;
  int rg = wave >> 1, ks = wave & 1;
  int rl = lane & 15, q = lane >> 4, r7 = rl & 7;
  int row0 = bid * 32 + rg * 16;
  const int K = K32 * 32;
  char* wbuf = smem + wave * 18432;         // 3 stages x (A 2KB + B 4KB)

  // gload lane mapping: instr covers 8 rows; lane l -> row l>>3, pos l&7.
  // pos p holds funit p^(row&7)  (row&7 == l>>3 for both instrs).
  int ra = lane >> 3, pa = lane & 7;
  int fsw = (pa ^ ra) * 4;                  // float offset of swizzled funit
  const float* asrc0 = A + (long)(row0 + ra)     * K + ks * (KH * 32) + fsw;
  const float* asrc1 = A + (long)(row0 + 8 + ra) * K + ks * (KH * 32) + fsw;
  const short* bsrc  = Bf + (long)ks * (KH * 2048) + lane * 8;

#define PSTAGE(KK, ST) { \
    char* ad = wbuf + (ST) * 6144; \
    GLOAD16(asrc0 + (KK) * 32, ad); \
    GLOAD16(asrc1 + (KK) * 32, ad + 1024); \
    char* bd = ad + 2048; \
    const short* bs = bsrc + (KK) * 2048; \
    GLOAD16(bs,        bd); \
    GLOAD16(bs + 512,  bd + 1024); \
    GLOAD16(bs + 1024, bd + 2048); \
    GLOAD16(bs + 1536, bd + 3072); \
  }

  f32x4 acc[4];
#pragma unroll
  for (int ct = 0; ct < 4; ++ct) acc[ct] = (f32x4){0.f, 0.f, 0.f, 0.f};

  PSTAGE(0, 0);
  PSTAGE(1, 1);
#pragma unroll
  for (int k = 0; k < KH; ++k) {
    if (k + 2 < KH) {
      PSTAGE(k + 2, (k + 2) % 3);
      asm volatile("s_waitcnt vmcnt(12)" ::: "memory");  // stage k landed
    } else if (k + 2 == KH) {
      asm volatile("s_waitcnt vmcnt(6)" ::: "memory");
    } else {
      asm volatile("s_waitcnt vmcnt(0)" ::: "memory");
    }
    __builtin_amdgcn_sched_barrier(0);
    const char* ab = wbuf + (k % 3) * 6144;
    f32x4 a0 = *(const f32x4*)(ab + rl * 128 + (((q * 2)     ^ r7) << 4));
    f32x4 a1 = *(const f32x4*)(ab + rl * 128 + (((q * 2 + 1) ^ r7) << 4));
    const char* bb = ab + 2048;
    s16x8 af;
    af[0]=f2bf(a0[0]); af[1]=f2bf(a0[1]); af[2]=f2bf(a0[2]); af[3]=f2bf(a0[3]);
    af[4]=f2bf(a1[0]); af[5]=f2bf(a1[1]); af[6]=f2bf(a1[2]); af[7]=f2bf(a1[3]);
#pragma unroll
    for (int ct = 0; ct < 4; ++ct) {
      s16x8 bfr = *(const s16x8*)(bb + ct * 1024 + lane * 16);
      acc[ct] = __builtin_amdgcn_mfma_f32_16x16x32_bf16(af, bfr, acc[ct], 0, 0, 0);
    }
  }
#undef PSTAGE

  // ---- K-split reduce: ks=1 dumps into its OWN (now idle) stage buffer ----
  if (ks == 1) {
#pragma unroll
    for (int ct = 0; ct < 4; ++ct)
      *(f32x4*)(wbuf + ct * 1024 + lane * 16) = acc[ct];
  }
  __syncthreads();
  if (ks == 0) {
    const char* pb = smem + (wave + 1) * 18432;   // partner's dump
#pragma unroll
    for (int ct = 0; ct < 4; ++ct) {
      f32x4 o = *(const f32x4*)(pb + ct * 1024 + lane * 16);
      int col = ct * 16 + rl;
      float bv = (col < 50) ? bias[col] : 0.f;
#pragma unroll
      for (int r = 0; r < 4; ++r) {
        int grow = row0 + q * 4 + r;               // D row = quad*4+reg (m89)
        float v = fmaxf(acc[ct][r] + o[r] + bv, 0.f);
        out[(long)grow * 64 + col] = (col < 50) ? v : 0.f;
      }
    }
  }
}

// MLP tail body: one block per batch row; sums the 23 per-job GEMM slices.
__device__ __forceinline__ void mix_body(
    int r, const float* __restrict__ pre,
    const float* __restrict__ b_gt, const float* __restrict__ b_gi,
    const float* __restrict__ W_m1, const float* __restrict__ b_m1,
    const float* __restrict__ W_m2, const float* __restrict__ b_m2,
    float* __restrict__ mix, float* smem) {
  float* sm = smem;            // [200]
  float* sh = smem + 200;      // [100]
  int t = threadIdx.x;
  if (t < 200) {
    float s1 = b_gt[t], s2 = b_gi[t];
#pragma unroll
    for (int j = 0; j < 7; ++j)  s1 += pre[(long)j * 25600 + r * 200 + t];
#pragma unroll
    for (int j = 7; j < 23; ++j) s2 += pre[(long)j * 25600 + r * 200 + t];
    sm[t] = fmaxf(s1, 0.f) + fmaxf(s2, 0.f);
  }
  __syncthreads();
  if (t < 100) {
    float a = b_m1[t];
#pragma unroll 4
    for (int k = 0; k < 200; ++k) a += sm[k] * W_m1[k * 100 + t];
    sh[t] = fmaxf(a, 0.f);
  }
  __syncthreads();
  if (t < 2) {
    float a = b_m2[t];
    for (int k = 0; k < 100; ++k) a += sh[k] * W_m2[k * 2 + t];
    mix[r * 2 + t] = a;
  }
}

// Grid order: img proj [0,144) first (longest: 32 steps/wave), txt proj
// [144,1168), mix [1168,1296) last (tiny).
__global__ __launch_bounds__(256)
void k_pm(
    const float* __restrict__ txt_region, const short* __restrict__ frt,
    const float* __restrict__ b_rt, float* __restrict__ tr,
    const float* __restrict__ img_region, const short* __restrict__ fri,
    const float* __restrict__ b_ri, float* __restrict__ ir,
    const float* __restrict__ pre,
    const float* __restrict__ b_gt, const float* __restrict__ b_gi,
    const float* __restrict__ W_m1, const float* __restrict__ b_m1,
    const float* __restrict__ W_m2, const float* __restrict__ b_m2,
    float* __restrict__ mix) {
  __shared__ __align__(16) char smem[73728];   // 4 waves x 18KB (3-stage ring)
  int bid = blockIdx.x;
  if (bid < 144)       proj_body<64>(img_region, fri, b_ri, ir, bid, smem);
  else if (bid < 1168) proj_body<24>(txt_region, frt, b_rt, tr, bid - 144, smem);
  else                 mix_body(bid - 1168, pre, b_gt, b_gi, W_m1, b_m1, W_m2, b_m2, mix, (float*)smem);
}

// ---------------------------------------------------------------------------
// k_sxx: XX Sinkhorn, 256 threads (one thread = one full column j).
// CT (f16, XOR-swizzled, stride 512B) = 128KB + Xf 32KB = exactly 160KB LDS.
// norms go via a tiny global scratch (LDS is full); after the MFMA phase the
// Xf region is re-used for sF/sG/alpha (double-buffered alpha -> ONE 4-wave
// barrier per max-plus iteration, no reduce phase at all). The i-loop runs
// only to ceil(n/8) (masked tail via alpha = -65504 -> -inf, never wins max).
// ---------------------------------------------------------------------------
__global__ __launch_bounds__(256) void k_sxx(
    const float* __restrict__ tr, const int* __restrict__ amask,
    float* __restrict__ norms_g, float* __restrict__ Sxx) {
  __shared__ __align__(16) char smem[163840];
  char*  CT = smem;                          // f16 CT[256][512B] XOR-swz
  short* Xf = (short*)(smem + 131072);       // 32 KB, dead after MFMA phase
  float*     sF   = (float*)(smem + 131072); // aliases Xf (loop phase only)
  float*     sG   = (float*)(smem + 132096);
  _Float16*  sA0  = (_Float16*)(smem + 133120);  // alpha double buffer
  _Float16*  sA1  = (_Float16*)(smem + 133632);
  int b = blockIdx.x, tid = threadIdx.x;
  int lane = tid & 63, wv = tid >> 6;
  int q = lane >> 4, rl = lane & 15;

  // ---- n: per-wave reduce (no LDS needed) ----
  int c = 0;
#pragma unroll
  for (int i = 0; i < 4; ++i) c += amask[b * 256 + i * 64 + lane];
#pragma unroll
  for (int o = 1; o < 64; o <<= 1) c += __shfl_xor(c, o);
  int n = __builtin_amdgcn_readfirstlane(c);

  // ---- stage Xf (bf16 MFMA frags of X) ----
  const float* Xg = tr + (long)b * 256 * 64;
  for (int slot = tid; slot < 2048; slot += 256) {
    int t = slot >> 7, k32 = (slot >> 6) & 1, l = slot & 63;
    int row = t * 16 + (l & 15), k0 = k32 * 32 + (l >> 4) * 8;
    const float* src = Xg + row * 64 + k0;
    f32x4 a0 = *(const f32x4*)src, a1 = *(const f32x4*)(src + 4);
    s16x8 p;
    p[0]=f2bf(a0[0]); p[1]=f2bf(a0[1]); p[2]=f2bf(a0[2]); p[3]=f2bf(a0[3]);
    p[4]=f2bf(a1[0]); p[5]=f2bf(a1[1]); p[6]=f2bf(a1[2]); p[7]=f2bf(a1[3]);
    *(s16x8*)(Xf + slot * 8) = p;
  }
  __syncthreads();

  float* ng = norms_g + b * 256;
  // ---- phase 1: diag tiles -> norms (global scratch) ----
#pragma unroll
  for (int si = 0; si < 4; ++si) {
    int st = wv * 4 + si;
    s16x8 a0 = *(const s16x8*)(Xf + ((st * 2 + 0) * 64 + lane) * 8);
    s16x8 a1 = *(const s16x8*)(Xf + ((st * 2 + 1) * 64 + lane) * 8);
    f32x4 d = (f32x4){0.f, 0.f, 0.f, 0.f};
    d = __builtin_amdgcn_mfma_f32_16x16x32_bf16(a0, a0, d, 0, 0, 0);
    d = __builtin_amdgcn_mfma_f32_16x16x32_bf16(a1, a1, d, 0, 0, 0);
#pragma unroll
    for (int r = 0; r < 4; ++r)
      if (rl == q * 4 + r) ng[st * 16 + q * 4 + r] = d[r];
  }
  __syncthreads();                           // drains vmcnt -> norms visible

  // per-thread norm sets (L2-hot)
  float nj[16];
#pragma unroll
  for (int ct = 0; ct < 16; ++ct) nj[ct] = ng[ct * 16 + rl];

  // ---- phase 2: full tiles per strip; write CT[j][i] f16 swizzled ----
#pragma unroll
  for (int si = 0; si < 4; ++si) {
    int st = wv * 4 + si;
    int i0w = st * 16 + q * 4;
    float ni0 = ng[i0w], ni1 = ng[i0w + 1], ni2 = ng[i0w + 2], ni3 = ng[i0w + 3];
    s16x8 a0 = *(const s16x8*)(Xf + ((st * 2 + 0) * 64 + lane) * 8);
    s16x8 a1 = *(const s16x8*)(Xf + ((st * 2 + 1) * 64 + lane) * 8);
    f32x4 acc[16];
#pragma unroll
    for (int ct = 0; ct < 16; ++ct) acc[ct] = (f32x4){0.f, 0.f, 0.f, 0.f};
#pragma unroll
    for (int ct = 0; ct < 16; ++ct) {
      s16x8 b0 = *(const s16x8*)(Xf + ((ct * 2 + 0) * 64 + lane) * 8);
      s16x8 b1 = *(const s16x8*)(Xf + ((ct * 2 + 1) * 64 + lane) * 8);
      acc[ct] = __builtin_amdgcn_mfma_f32_16x16x32_bf16(a0, b0, acc[ct], 0, 0, 0);
      acc[ct] = __builtin_amdgcn_mfma_f32_16x16x32_bf16(a1, b1, acc[ct], 0, 0, 0);
    }
#pragma unroll
    for (int ct = 0; ct < 16; ++ct) {
      int j = ct * 16 + rl;
      float njv = nj[ct];
      float v0 = (acc[ct][0] - 0.5f * (ni0 + njv)) * INV_EPS_LN2;
      float v1 = (acc[ct][1] - 0.5f * (ni1 + njv)) * INV_EPS_LN2;
      float v2 = (acc[ct][2] - 0.5f * (ni2 + njv)) * INV_EPS_LN2;
      float v3 = (acc[ct][3] - 0.5f * (ni3 + njv)) * INV_EPS_LN2;
      char* p = CT + (((j << 9) + (i0w << 1)) ^ ((j & 7) << 4));
      *(unsigned*)(p)     = (unsigned)f2h(v0) | ((unsigned)f2h(v1) << 16);
      *(unsigned*)(p + 4) = (unsigned)f2h(v2) | ((unsigned)f2h(v3) << 16);
    }
  }
  __syncthreads();                           // Xf dead; CT complete

  // ---- init loop state (aliases Xf region) ----
  float log2n = log2f((float)n);
  sF[tid] = 0.f; sG[tid] = 0.f;
  sA0[tid] = (tid < n) ? (_Float16)(-log2n) : (_Float16)(-65504.f);
  sA1[tid] = (_Float16)(-65504.f);
  __syncthreads();

  // ---- 40 max-plus half-steps: thread = column j, one barrier/iter ----
  int j = tid;
  unsigned base = (unsigned)(j << 9);
  unsigned sw   = (unsigned)((j & 7) << 4);
  int ns = (n + 7) >> 3;
  for (int h = 0; h < 40; ++h) {
    const unsigned* ah2 = (const unsigned*)((h & 1) ? sA1 : sA0);
    _Float16* aout = (h & 1) ? sA0 : sA1;
    if (j < n) {
      unsigned mm = 0xFBFFFBFFu;             // {-65504, -65504}
      for (int s = 0; s < ns; ++s) {
        u32x4 v = *(const u32x4*)(CT + ((base + (unsigned)(s << 4)) ^ sw));
        unsigned a0 = ah2[s * 4 + 0], a1 = ah2[s * 4 + 1];
        unsigned a2 = ah2[s * 4 + 2], a3 = ah2[s * 4 + 3];
        unsigned t0, t1, t2, t3;
        asm("v_pk_add_f16 %0, %1, %2" : "=v"(t0) : "v"(v[0]), "v"(a0));
        asm("v_pk_add_f16 %0, %1, %2" : "=v"(t1) : "v"(v[1]), "v"(a1));
        asm("v_pk_add_f16 %0, %1, %2" : "=v"(t2) : "v"(v[2]), "v"(a2));
        asm("v_pk_add_f16 %0, %1, %2" : "=v"(t3) : "v"(v[3]), "v"(a3));
        asm("v_pk_max_f16 %0, %0, %1" : "+v"(mm) : "v"(t0));
        asm("v_pk_max_f16 %0, %0, %1" : "+v"(mm) : "v"(t1));
        asm("v_pk_max_f16 %0, %0, %1" : "+v"(mm) : "v"(t2));
        asm("v_pk_max_f16 %0, %0, %1" : "+v"(mm) : "v"(t3));
      }
      float m = fmaxf(h2f((unsigned short)(mm & 0xFFFFu)),
                      h2f((unsigned short)(mm >> 16)));
      ((h & 1) ? sF : sG)[j] = -EPS_LN2 * m;
      aout[j] = (_Float16)(-log2n - m);
    }
    __syncthreads();
  }
  if (tid < 64) {
    float a = 0.f;
    for (int i = tid; i < n; i += 64) a += sF[i] + sG[i];
#pragma unroll
    for (int o = 1; o < 64; o <<= 1) a += __shfl_xor(a, o);
    if (tid == 0) Sxx[b] = a / n;
  }
}

// ---------------------------------------------------------------------------
// k_sxy: XY (blocks [0,128)) and YY (blocks [128,256)) Sinkhorn, unchanged.
// ---------------------------------------------------------------------------
#define SK_SMEM 50736

__global__ __launch_bounds__(1024) void k_sxy(
    const float* __restrict__ tr, const float* __restrict__ ir,
    const int* __restrict__ amask,
    float* __restrict__ Sxy, float* __restrict__ Syy) {
  __shared__ __align__(16) char smem[SK_SMEM];
  int role = blockIdx.x >> 7;
  int b    = blockIdx.x & 127;
  int tid  = threadIdx.x;

  if (role == 0) {
    // ====================== XY ======================
    float* Ys  = (float*)smem;                    // [36][64]
    float* Cs  = (float*)(smem + 9216);           // [256][37]
    float* nx  = (float*)(smem + 47104);          // [256]
    float* ny  = (float*)(smem + 48128);          // [36]
    float* sA  = (float*)(smem + 48288);          // padded alpha [272]
    float* sB  = (float*)(smem + 49376);          // beta [36]
    float* sF  = (float*)(smem + 49536);          // [256]
    float* sG  = (float*)(smem + 50560);          // [36]
    int*   nsh = (int*)  (smem + 50720);
    if (tid < 64) {
      int c = 0;
      for (int i = tid; i < 256; i += 64) c += amask[b * 256 + i];
#pragma unroll
      for (int o = 1; o < 64; o <<= 1) c += __shfl_xor(c, o);
      if (tid == 0) *nsh = c;
    }
    const float* Xg = tr + (long)b * 256 * 64;
    const float* Yg = ir + (long)b * 36 * 64;
    for (int idx = tid; idx < 576; idx += 1024) {
      int row = idx >> 4, q4 = idx & 15;
      *(f32x4*)(Ys + row * 64 + q4 * 4) = *(const f32x4*)(Yg + row * 64 + q4 * 4);
    }
    __syncthreads();
    int n = *nsh;
    if (tid < 256) {
      float a = 0.f;
#pragma unroll
      for (int q4 = 0; q4 < 13; ++q4) {
        f32x4 v = *(const f32x4*)(Xg + tid * 64 + q4 * 4);
        a += v[0]*v[0] + v[1]*v[1] + v[2]*v[2] + v[3]*v[3];
      }
      nx[tid] = a;
    } else if (tid < 292) {
      int jj = tid - 256; float a = 0.f;
#pragma unroll
      for (int q4 = 0; q4 < 13; ++q4) {
        f32x4 v = *(const f32x4*)(Ys + jj * 64 + q4 * 4);
        a += v[0]*v[0] + v[1]*v[1] + v[2]*v[2] + v[3]*v[3];
      }
      ny[jj] = a;
    }
    __syncthreads();
    if (tid < 1008) {
      int ii = tid / 36, jj = tid - ii * 36;
      f32x4 yr[13];
#pragma unroll
      for (int q4 = 0; q4 < 13; ++q4) yr[q4] = *(const f32x4*)(Ys + jj * 64 + q4 * 4);
      float nyj = ny[jj];
      for (int i = ii; i < 256; i += 28) {
        float d = 0.f;
#pragma unroll
        for (int q4 = 0; q4 < 13; ++q4) {
          f32x4 xv = *(const f32x4*)(Xg + i * 64 + q4 * 4);
          d += xv[0]*yr[q4][0] + xv[1]*yr[q4][1] + xv[2]*yr[q4][2] + xv[3]*yr[q4][3];
        }
        Cs[i * 37 + jj] = (d - 0.5f * (nx[i] + nyj)) * INV_EPS_LN2;
      }
    }
    __syncthreads();
    int jg = tid >> 4, kg = tid & 15;             // g-role: column jg, slice kg
    float Cg[16];
    if (jg < 36) {
#pragma unroll
      for (int t = 0; t < 16; ++t) Cg[t] = Cs[(kg * 16 + t) * 37 + jg];
    }
    int fi = tid >> 2, kf = tid & 3;              // f-role: row fi, slice kf
    float Cf[9];
#pragma unroll
    for (int t = 0; t < 9; ++t) {
      int jj2 = kf * 9 + t;
      Cf[t] = (jj2 < 36) ? Cs[fi * 37 + jj2] : 0.f;
    }
    float log2n = log2f((float)n);
    if (tid < 256) { sF[tid] = 0.f; sA[tid + (tid >> 4)] = -log2n; }
    __syncthreads();
    const float* agp = sA + kg * 17;
    int gend = n - kg * 16; if (gend > 16) gend = 16;
    for (int it = 0; it < 20; ++it) {
      float gm = -1e30f;
      if (jg < 36) {
#pragma unroll
        for (int t = 0; t < 16; ++t)
          if (t < gend) gm = fmaxf(gm, agp[t] + Cg[t]);
        gm = fmaxf(gm, __shfl_xor(gm, 1)); gm = fmaxf(gm, __shfl_xor(gm, 2));
        gm = fmaxf(gm, __shfl_xor(gm, 4)); gm = fmaxf(gm, __shfl_xor(gm, 8));
      }
      __syncthreads();
      if (jg < 36 && kg == 0) {
        sG[jg] = -EPS_LN2 * gm;
        sB[jg] = -LOG2_36 - gm;
      }
      __syncthreads();
      float fm = -1e30f;
#pragma unroll
      for (int t = 0; t < 9; ++t) {
        int jj2 = kf * 9 + t;
        if (jj2 < 36) fm = fmaxf(fm, sB[jj2] + Cf[t]);
      }
      fm = fmaxf(fm, __shfl_xor(fm, 1)); fm = fmaxf(fm, __shfl_xor(fm, 2));
      __syncthreads();
      if (kf == 0 && fi < n) {
        sF[fi] = -EPS_LN2 * fm;
        sA[fi + (fi >> 4)] = -log2n - fm;
      }
      __syncthreads();
    }
    if (tid < 64) {
      float a = 0.f;
      for (int i = tid; i < n; i += 64) a += sF[i];
      float g = (tid < 36) ? sG[tid] : 0.f;
#pragma unroll
      for (int o = 1; o < 64; o <<= 1) { a += __shfl_xor(a, o); g += __shfl_xor(g, o); }
      if (tid == 0) Sxy[b] = a / n + g / 36.f;
    }
  } else {
    // ====================== YY ======================
    float* Ys = (float*)smem;                     // [36][64]
    float* Cs = (float*)(smem + 9216);            // [36][37]
    float* ny = (float*)(smem + 48128);
    float* sA = (float*)(smem + 48288);           // [36]
    float* sF = (float*)(smem + 49536);
    float* sG = (float*)(smem + 50560);
    const float* Yg = ir + (long)b * 36 * 64;
    for (int idx = tid; idx < 576; idx += 1024) {
      int row = idx >> 4, q4 = idx & 15;
      *(f32x4*)(Ys + row * 64 + q4 * 4) = *(const f32x4*)(Yg + row * 64 + q4 * 4);
    }
    __syncthreads();
    if (tid < 36) {
      float a = 0.f;
#pragma unroll
      for (int q4 = 0; q4 < 13; ++q4) {
        f32x4 v = *(const f32x4*)(Ys + tid * 64 + q4 * 4);
        a += v[0]*v[0] + v[1]*v[1] + v[2]*v[2] + v[3]*v[3];
      }
      ny[tid] = a;
    }
    __syncthreads();
    if (tid < 1008) {
      int ii = tid / 36, jj = tid - ii * 36;
      f32x4 yr[13];
#pragma unroll
      for (int q4 = 0; q4 < 13; ++q4) yr[q4] = *(const f32x4*)(Ys + jj * 64 + q4 * 4);
      float nyj = ny[jj];
      for (int i = ii; i < 36; i += 28) {
        float d = 0.f;
#pragma unroll
        for (int q4 = 0; q4 < 13; ++q4) {
          f32x4 xv = *(const f32x4*)(Ys + i * 64 + q4 * 4);
          d += xv[0]*yr[q4][0] + xv[1]*yr[q4][1] + xv[2]*yr[q4][2] + xv[3]*yr[q4][3];
        }
        Cs[i * 37 + jj] = (d - 0.5f * (ny[i] + nyj)) * INV_EPS_LN2;
      }
    }
    __syncthreads();
    int j = tid >> 2, kk = tid & 3;
    float Creg[9];
    if (j < 36) {
#pragma unroll
      for (int t = 0; t < 9; ++t) {
        int i2 = kk * 9 + t;
        Creg[t] = (i2 < 36) ? Cs[i2 * 37 + j] : 0.f;
      }
    }
    if (tid < 36) { sF[tid] = 0.f; sA[tid] = -LOG2_36; }
    __syncthreads();
    for (int h = 0; h < 40; ++h) {
      float m = -1e30f;
      if (j < 36) {
#pragma unroll
        for (int t = 0; t < 9; ++t) {
          int i2 = kk * 9 + t;
          if (i2 < 36) m = fmaxf(m, sA[i2] + Creg[t]);
        }
        m = fmaxf(m, __shfl_xor(m, 1)); m = fmaxf(m, __shfl_xor(m, 2));
      }
      __syncthreads();
      if (j < 36 && kk == 0) {
        ((h & 1) ? sF : sG)[j] = -EPS_LN2 * m;
        sA[j] = -LOG2_36 - m;
      }
      __syncthreads();
    }
    if (tid < 64) {
      float a = (tid < 36) ? sF[tid] + sG[tid] : 0.f;
#pragma unroll
      for (int o = 1; o < 64; o <<= 1) a += __shfl_xor(a, o);
      if (tid == 0) Syy[b] = a / 36.f;
    }
  }
}

// ---------------------------------------------------------------------------
// Final combine: w_dis -> w_pred, max with mix_pred, 2-way softmax.
// ---------------------------------------------------------------------------
__global__ void k_final(const float* __restrict__ mix, const float* __restrict__ sxy,
                        const float* __restrict__ sxx, const float* __restrict__ syy,
                        float* __restrict__ out) {
  int b = blockIdx.x * 64 + threadIdx.x;
  if (b < 128) {
    float w  = sxy[b] - 0.5f * (sxx[b] + syy[b]);
    float x0 = fmaxf(mix[b * 2 + 0], 1.0f - 0.01f * w);
    float x1 = fmaxf(mix[b * 2 + 1], 0.01f * w);
    float mx = fmaxf(x0, x1);
    float e0 = expf(x0 - mx), e1 = expf(x1 - mx);
    float inv = 1.f / (e0 + e1);
    out[b * 2 + 0] = e0 * inv;
    out[b * 2 + 1] = e1 * inv;
  }
}

// ---------------------------------------------------------------------------
extern "C" void kernel_launch(void* const* d_in, const int* in_sizes, int n_in,
                              void* d_out, int out_size, void* d_ws, size_t ws_size,
                              hipStream_t stream) {
  const float* txt_global = (const float*)d_in[0];
  const float* txt_region = (const float*)d_in[1];
  const float* img_global = (const float*)d_in[2];
  const float* img_region = (const float*)d_in[3];
  const float* social     = (const float*)d_in[4];
  const int*   attn_mask  = (const int*)  d_in[5];
  const float* W_stat = (const float*)d_in[6];  const float* b_stat = (const float*)d_in[7];
  const float* W_gt   = (const float*)d_in[8];  const float* b_gt   = (const float*)d_in[9];
  const float* W_gi   = (const float*)d_in[10]; const float* b_gi   = (const float*)d_in[11];
  const float* W_rt   = (const float*)d_in[12]; const float* b_rt   = (const float*)d_in[13];
  const float* W_ri   = (const float*)d_in[14]; const float* b_ri   = (const float*)d_in[15];
  const float* W_m1   = (const float*)d_in[16]; const float* b_m1   = (const float*)d_in[17];
  const float* W_m2   = (const float*)d_in[18]; const float* b_m2   = (const float*)d_in[19];

  float* ws = (float*)d_ws;
  float* ws_mix = ws;                    // 256
  float* ws_sxy = ws + 256;              // 128
  float* ws_sxx = ws + 384;              // 128
  float* ws_syy = ws + 512;              // 128
  short* ws_frt = (short*)(ws + 1024);   // 49152 shorts -> ends float 25600
  short* ws_fri = (short*)(ws + 25600);  // 131072 shorts -> ends float 91136
  float* ws_tr  = ws + 131072;           // [32768][64]
  float* ws_ir  = ws + 2228224;          // [4608][64]
  float* ws_pre = ws + 2523136;          // [23][128][200]
  float* ws_nrm = ws + 3111936;          // [128][256] norms scratch

  k_prep<<<456, 256, 0, stream>>>(W_rt, W_ri, ws_frt, ws_fri,
                                  txt_global, img_global, social,
                                  W_stat, b_stat, W_gt, W_gi, ws_pre);
  k_pm<<<1296, 256, 0, stream>>>(txt_region, ws_frt, b_rt, ws_tr,
                                 img_region, ws_fri, b_ri, ws_ir,
                                 ws_pre, b_gt, b_gi,
                                 W_m1, b_m1, W_m2, b_m2, ws_mix);
  k_sxx<<<128, 256, 0, stream>>>(ws_tr, attn_mask, ws_nrm, ws_sxx);
  k_sxy<<<256, 1024, 0, stream>>>(ws_tr, ws_ir, attn_mask, ws_sxy, ws_syy);
  k_final<<<2, 64, 0, stream>>>(ws_mix, ws_sxy, ws_sxx, ws_syy, (float*)d_out);
}

// Round 9
// 366.491 us; speedup vs baseline: 1.0904x; 1.0904x over previous
//
#include <hip/hip_runtime.h>

typedef float        f32x4 __attribute__((ext_vector_type(4)));
typedef short        s16x8 __attribute__((ext_vector_type(8)));
typedef unsigned int u32x4 __attribute__((ext_vector_type(4)));

#define EPS_LN2      0.0017328679513998632f   /* eps*ln2, eps = 0.0025 */
#define INV_EPS_LN2  577.0780163555852f       /* 1/(eps*ln2) */
#define LOG2_36      5.169925001442312f

__device__ __forceinline__ short f2bf(float x) {
  unsigned int u; __builtin_memcpy(&u, &x, 4);
  u = (u + 0x7FFFu + ((u >> 16) & 1u)) >> 16;   // RNE
  return (short)u;
}

__device__ __forceinline__ unsigned short f2h(float x) {
  return __builtin_bit_cast(unsigned short, (_Float16)x);
}
__device__ __forceinline__ float h2f(unsigned short h) {
  return (float)__builtin_bit_cast(_Float16, h);
}

// ---------------------------------------------------------------------------
// k_prep: blocks [0,88) pack W_rt/W_ri into MFMA B-frag order (bf16);
// blocks [88,456) K-split GEMM writing per-job slices pre[23][128][200].
// ---------------------------------------------------------------------------
__global__ __launch_bounds__(256) void k_prep(
    const float* __restrict__ W_rt, const float* __restrict__ W_ri,
    short* __restrict__ frt, short* __restrict__ fri,
    const float* __restrict__ txt, const float* __restrict__ img,
    const float* __restrict__ social,
    const float* __restrict__ W_stat, const float* __restrict__ b_stat,
    const float* __restrict__ W_gt, const float* __restrict__ W_gi,
    float* __restrict__ pre) {
  __shared__ float sA[32][128];
  int bid = blockIdx.x;
  if (bid < 88) {
    int slot = bid * 256 + threadIdx.x;   // 22528 total
    const float* W; short* dst; int f;
    if (slot < 6144) { W = W_rt; dst = frt; f = slot; }
    else             { W = W_ri; dst = fri; f = slot - 6144; }
    int k32 = f >> 8, rem = f & 255, ct = rem >> 6, l = rem & 63;
    int col = ct * 16 + (l & 15);
    int k0  = k32 * 32 + (l >> 4) * 8;
    s16x8 p;
#pragma unroll
    for (int c = 0; c < 8; ++c) {
      float v = (col < 50) ? W[(k0 + c) * 50 + col] : 0.f;
      p[c] = f2bf(v);
    }
    *(s16x8*)(dst + (long)f * 8) = p;
    return;
  }
  int gb = bid - 88;
  int job = gb >> 4, rb = (gb >> 2) & 3, cb = gb & 3;
  int t = threadIdx.x, r0 = rb * 32;
  const float* W; int k0, klen;
  if (job < 6)       { k0 = job * 128;       klen = 128; W = W_gt; }
  else if (job == 6) { k0 = 0;               klen = 100; W = W_gt + 768 * 200; }
  else               { k0 = (job - 7) * 128; klen = 128; W = W_gi; }
  if (job == 6) {
    for (int idx = t; idx < 4096; idx += 256) {
      int r = idx >> 7, k = idx & 127;
      float v = 0.f;
      if (k < 100) {
        v = b_stat[k];
#pragma unroll
        for (int u = 0; u < 10; ++u) v += social[(r0 + r) * 10 + u] * W_stat[u * 100 + k];
        v = fmaxf(v, 0.f);
      }
      sA[r][k] = v;
    }
  } else {
    const float* A = (job < 6) ? txt : img;
    int K_A = (job < 6) ? 768 : 2048;
    for (int idx = t; idx < 4096; idx += 256) {
      int r = idx >> 7, k = idx & 127;
      sA[r][k] = A[(r0 + r) * K_A + k0 + k];
    }
  }
  __syncthreads();
  int c = cb * 64 + (t & 63), rg = t >> 6;
  if (c < 200) {
    float acc[8];
#pragma unroll
    for (int i = 0; i < 8; ++i) acc[i] = 0.f;
    for (int k4 = 0; k4 < klen; k4 += 4) {
      float w0 = W[(k0 + k4    ) * 200 + c];
      float w1 = W[(k0 + k4 + 1) * 200 + c];
      float w2 = W[(k0 + k4 + 2) * 200 + c];
      float w3 = W[(k0 + k4 + 3) * 200 + c];
#pragma unroll
      for (int i = 0; i < 8; ++i) {
        f32x4 a = *(const f32x4*)&sA[rg * 8 + i][k4];
        acc[i] += a[0]*w0 + a[1]*w1 + a[2]*w2 + a[3]*w3;
      }
    }
    float* dst = pre + (long)job * 25600;
#pragma unroll
    for (int i = 0; i < 8; ++i)
      dst[(r0 + rg * 8 + i) * 200 + c] = acc[i];
  }
}

// ---------------------------------------------------------------------------
// Projection GEMM: 3-slot REGISTER ring filled by inline-asm
// global_load_dwordx4 (opaque to the compiler -> it cannot JIT-serialize the
// pipeline or insert conservative vmcnt(0) drains, the failure mode of every
// prior round). Counted s_waitcnt vmcnt(12) keeps 2 stages (12 loads) in
// flight per wave; sched_barrier(0) fences the consumers (rule #18).
// No LDS staging; 8KB end-reduce only. One block = 32 rows x 2 row-groups
// x 2 K-halves (4 waves). out[M][64] = relu(A[M][K] @ W + bias).
// ---------------------------------------------------------------------------
template<int K32>
__device__ __forceinline__ void proj_body(const float* __restrict__ A,
                                          const short* __restrict__ Bf,
                                          const float* __restrict__ bias,
                                          float* __restrict__ out, int bid,
                                          float* __restrict__ red) {
  constexpr int KH = K32 / 2;               // k32 steps per wave
  int wave = threadIdx.x >> 6, lane = threadIdx.x & 63;
  int rg = wave >> 1, ks = wave & 1;
  int rl = lane & 15, q = lane >> 4;
  int row0 = bid * 32 + rg * 16;
  const int K = K32 * 32;
  const float* ar = A + (long)(row0 + rl) * K + ks * (KH * 32) + q * 8;
  const s16x8* bp = (const s16x8*)Bf + ks * (KH * 256) + lane;

  f32x4 pa0[3], pa1[3];
  s16x8 pb0[3], pb1[3], pb2[3], pb3[3];

#define GLF(D, P) asm volatile("global_load_dwordx4 %0, %1, off" \
                               : "=&v"(D) : "v"(P) : "memory")
#define ISSUE(KK, S) { \
    const float* ap_ = ar + (KK) * 32; \
    GLF(pa0[S], ap_); GLF(pa1[S], ap_ + 4); \
    const s16x8* bp_ = bp + (KK) * 256; \
    GLF(pb0[S], bp_); GLF(pb1[S], bp_ + 64); \
    GLF(pb2[S], bp_ + 128); GLF(pb3[S], bp_ + 192); }

  f32x4 acc[4];
#pragma unroll
  for (int ct = 0; ct < 4; ++ct) acc[ct] = (f32x4){0.f, 0.f, 0.f, 0.f};

  ISSUE(0, 0);
  ISSUE(1, 1);
#pragma unroll
  for (int k = 0; k < KH; ++k) {
    if (k + 2 < KH) {
      ISSUE(k + 2, (k + 2) % 3);
      asm volatile("s_waitcnt vmcnt(12)" ::: "memory");  // slot k landed
    } else if (k + 2 == KH) {
      asm volatile("s_waitcnt vmcnt(6)" ::: "memory");
    } else {
      asm volatile("s_waitcnt vmcnt(0)" ::: "memory");
    }
    __builtin_amdgcn_sched_barrier(0);
    int s = k % 3;                          // compile-time after unroll
    s16x8 af;
    af[0]=f2bf(pa0[s][0]); af[1]=f2bf(pa0[s][1]);
    af[2]=f2bf(pa0[s][2]); af[3]=f2bf(pa0[s][3]);
    af[4]=f2bf(pa1[s][0]); af[5]=f2bf(pa1[s][1]);
    af[6]=f2bf(pa1[s][2]); af[7]=f2bf(pa1[s][3]);
    acc[0] = __builtin_amdgcn_mfma_f32_16x16x32_bf16(af, pb0[s], acc[0], 0, 0, 0);
    acc[1] = __builtin_amdgcn_mfma_f32_16x16x32_bf16(af, pb1[s], acc[1], 0, 0, 0);
    acc[2] = __builtin_amdgcn_mfma_f32_16x16x32_bf16(af, pb2[s], acc[2], 0, 0, 0);
    acc[3] = __builtin_amdgcn_mfma_f32_16x16x32_bf16(af, pb3[s], acc[3], 0, 0, 0);
  }
#undef ISSUE
#undef GLF

  // ---- K-split reduce: ks=1 dumps partials, ks=0 combines + writes ----
  float* rb = red + rg * 1024;              // [64][16] per row-group
  if (ks == 1) {
#pragma unroll
    for (int ct = 0; ct < 4; ++ct)
      *(f32x4*)(rb + lane * 16 + ct * 4) = acc[ct];
  }
  __syncthreads();
  if (ks == 0) {
#pragma unroll
    for (int ct = 0; ct < 4; ++ct) {
      f32x4 o = *(const f32x4*)(rb + lane * 16 + ct * 4);
      int col = ct * 16 + rl;
      float bv = (col < 50) ? bias[col] : 0.f;
#pragma unroll
      for (int r = 0; r < 4; ++r) {
        int grow = row0 + q * 4 + r;         // D row = quad*4+reg (m89)
        float v = fmaxf(acc[ct][r] + o[r] + bv, 0.f);
        out[(long)grow * 64 + col] = (col < 50) ? v : 0.f;
      }
    }
  }
}

// MLP tail body: one block per batch row; sums the 23 per-job GEMM slices.
__device__ __forceinline__ void mix_body(
    int r, const float* __restrict__ pre,
    const float* __restrict__ b_gt, const float* __restrict__ b_gi,
    const float* __restrict__ W_m1, const float* __restrict__ b_m1,
    const float* __restrict__ W_m2, const float* __restrict__ b_m2,
    float* __restrict__ mix, float* smem) {
  float* sm = smem;            // [200]
  float* sh = smem + 200;      // [100]
  int t = threadIdx.x;
  if (t < 200) {
    float s1 = b_gt[t], s2 = b_gi[t];
#pragma unroll
    for (int j = 0; j < 7; ++j)  s1 += pre[(long)j * 25600 + r * 200 + t];
#pragma unroll
    for (int j = 7; j < 23; ++j) s2 += pre[(long)j * 25600 + r * 200 + t];
    sm[t] = fmaxf(s1, 0.f) + fmaxf(s2, 0.f);
  }
  __syncthreads();
  if (t < 100) {
    float a = b_m1[t];
#pragma unroll 4
    for (int k = 0; k < 200; ++k) a += sm[k] * W_m1[k * 100 + t];
    sh[t] = fmaxf(a, 0.f);
  }
  __syncthreads();
  if (t < 2) {
    float a = b_m2[t];
    for (int k = 0; k < 100; ++k) a += sh[k] * W_m2[k * 2 + t];
    mix[r * 2 + t] = a;
  }
}

// Grid order: img proj [0,144) first (longest: 32 steps/wave), txt proj
// [144,1168), mix [1168,1296) last (tiny).
__global__ __launch_bounds__(256)
void k_pm(
    const float* __restrict__ txt_region, const short* __restrict__ frt,
    const float* __restrict__ b_rt, float* __restrict__ tr,
    const float* __restrict__ img_region, const short* __restrict__ fri,
    const float* __restrict__ b_ri, float* __restrict__ ir,
    const float* __restrict__ pre,
    const float* __restrict__ b_gt, const float* __restrict__ b_gi,
    const float* __restrict__ W_m1, const float* __restrict__ b_m1,
    const float* __restrict__ W_m2, const float* __restrict__ b_m2,
    float* __restrict__ mix) {
  __shared__ __align__(16) float red[2048];   // 8 KB reduce / mix scratch
  int bid = blockIdx.x;
  if (bid < 144)       proj_body<64>(img_region, fri, b_ri, ir, bid, red);
  else if (bid < 1168) proj_body<24>(txt_region, frt, b_rt, tr, bid - 144, red);
  else                 mix_body(bid - 1168, pre, b_gt, b_gi, W_m1, b_m1, W_m2, b_m2, mix, red);
}

// ---------------------------------------------------------------------------
// k_sxx: XX Sinkhorn, 512 threads (8 waves -- round 7's 256-thread version
// had 1 wave/SIMD and latency-starved at 98us). Column j = tid&255, i-range
// split 2 ways (kk = tid>>8), small LDS reduce, 2 barriers/iter.
// CT (f16, XOR-swizzled, stride 512B) = 128KB; Xf 32KB (dead after MFMA
// phase, re-used for loop state). Norms live briefly in the not-yet-written
// CT region and are register-preloaded behind a barrier -- no global traffic.
// ---------------------------------------------------------------------------
__global__ __launch_bounds__(512) void k_sxx(
    const float* __restrict__ tr, const int* __restrict__ amask,
    float* __restrict__ Sxx) {
  __shared__ __align__(16) char smem[163840];
  char*  CT    = smem;                       // f16 CT[256][512B] XOR-swz
  float* norms = (float*)smem;               // temp, inside CT region
  short* Xf    = (short*)(smem + 131072);    // 32 KB, dead after MFMA phase
  float*     sPm = (float*)(smem + 131072);  // [2][256] aliases Xf
  float*     sF  = (float*)(smem + 133120);
  float*     sG  = (float*)(smem + 134144);
  _Float16*  sAh = (_Float16*)(smem + 135168);
  int b = blockIdx.x, tid = threadIdx.x;
  int lane = tid & 63, wv = tid >> 6;
  int q = lane >> 4, rl = lane & 15;

  // ---- n: per-wave reduce ----
  int c = 0;
#pragma unroll
  for (int i = 0; i < 4; ++i) c += amask[b * 256 + i * 64 + lane];
#pragma unroll
  for (int o = 1; o < 64; o <<= 1) c += __shfl_xor(c, o);
  int n = __builtin_amdgcn_readfirstlane(c);

  // ---- stage Xf (bf16 MFMA frags of X) ----
  const float* Xg = tr + (long)b * 256 * 64;
  for (int slot = tid; slot < 2048; slot += 512) {
    int t = slot >> 7, k32 = (slot >> 6) & 1, l = slot & 63;
    int row = t * 16 + (l & 15), k0 = k32 * 32 + (l >> 4) * 8;
    const float* src = Xg + row * 64 + k0;
    f32x4 a0 = *(const f32x4*)src, a1 = *(const f32x4*)(src + 4);
    s16x8 p;
    p[0]=f2bf(a0[0]); p[1]=f2bf(a0[1]); p[2]=f2bf(a0[2]); p[3]=f2bf(a0[3]);
    p[4]=f2bf(a1[0]); p[5]=f2bf(a1[1]); p[6]=f2bf(a1[2]); p[7]=f2bf(a1[3]);
    *(s16x8*)(Xf + slot * 8) = p;
  }
  __syncthreads();

  // ---- phase 1: diag tiles -> norms (in CT region, not yet written) ----
#pragma unroll
  for (int si = 0; si < 2; ++si) {
    int st = wv * 2 + si;
    s16x8 a0 = *(const s16x8*)(Xf + ((st * 2 + 0) * 64 + lane) * 8);
    s16x8 a1 = *(const s16x8*)(Xf + ((st * 2 + 1) * 64 + lane) * 8);
    f32x4 d = (f32x4){0.f, 0.f, 0.f, 0.f};
    d = __builtin_amdgcn_mfma_f32_16x16x32_bf16(a0, a0, d, 0, 0, 0);
    d = __builtin_amdgcn_mfma_f32_16x16x32_bf16(a1, a1, d, 0, 0, 0);
#pragma unroll
    for (int r = 0; r < 4; ++r)
      if (rl == q * 4 + r) norms[st * 16 + q * 4 + r] = d[r];
  }
  __syncthreads();

  // preload ALL norms this thread needs into registers, then barrier so
  // phase-2 CT writes can safely clobber the norms slice.
  float nj[16];
#pragma unroll
  for (int ct = 0; ct < 16; ++ct) nj[ct] = norms[ct * 16 + rl];
  float ni[2][4];
#pragma unroll
  for (int si = 0; si < 2; ++si) {
    int base = (wv * 2 + si) * 16 + q * 4;
#pragma unroll
    for (int r = 0; r < 4; ++r) ni[si][r] = norms[base + r];
  }
  __syncthreads();

  // ---- phase 2: full tiles per strip; write CT[j][i] f16 swizzled ----
#pragma unroll
  for (int si = 0; si < 2; ++si) {
    int st = wv * 2 + si;
    int i0w = st * 16 + q * 4;
    s16x8 a0 = *(const s16x8*)(Xf + ((st * 2 + 0) * 64 + lane) * 8);
    s16x8 a1 = *(const s16x8*)(Xf + ((st * 2 + 1) * 64 + lane) * 8);
    f32x4 acc[16];
#pragma unroll
    for (int ct = 0; ct < 16; ++ct) acc[ct] = (f32x4){0.f, 0.f, 0.f, 0.f};
#pragma unroll
    for (int ct = 0; ct < 16; ++ct) {
      s16x8 b0 = *(const s16x8*)(Xf + ((ct * 2 + 0) * 64 + lane) * 8);
      s16x8 b1 = *(const s16x8*)(Xf + ((ct * 2 + 1) * 64 + lane) * 8);
      acc[ct] = __builtin_amdgcn_mfma_f32_16x16x32_bf16(a0, b0, acc[ct], 0, 0, 0);
      acc[ct] = __builtin_amdgcn_mfma_f32_16x16x32_bf16(a1, b1, acc[ct], 0, 0, 0);
    }
#pragma unroll
    for (int ct = 0; ct < 16; ++ct) {
      int j = ct * 16 + rl;
      float njv = nj[ct];
      float v0 = (acc[ct][0] - 0.5f * (ni[si][0] + njv)) * INV_EPS_LN2;
      float v1 = (acc[ct][1] - 0.5f * (ni[si][1] + njv)) * INV_EPS_LN2;
      float v2 = (acc[ct][2] - 0.5f * (ni[si][2] + njv)) * INV_EPS_LN2;
      float v3 = (acc[ct][3] - 0.5f * (ni[si][3] + njv)) * INV_EPS_LN2;
      char* p = CT + (((j << 9) + (i0w << 1)) ^ ((j & 7) << 4));
      *(unsigned*)(p)     = (unsigned)f2h(v0) | ((unsigned)f2h(v1) << 16);
      *(unsigned*)(p + 4) = (unsigned)f2h(v2) | ((unsigned)f2h(v3) << 16);
    }
  }
  __syncthreads();                           // Xf dead; CT complete

  // ---- init loop state (aliases Xf region) ----
  float log2n = log2f((float)n);
  if (tid < 256) {
    sF[tid] = 0.f; sG[tid] = 0.f;
    sAh[tid] = (tid < n) ? (_Float16)(-log2n) : (_Float16)(-65504.f);
  }
  __syncthreads();

  // ---- 40 max-plus half-steps: column j, 2-way i-split, packed f16 ----
  int kk = tid >> 8, j = tid & 255;
  unsigned base = (unsigned)(j << 9);
  unsigned sw   = (unsigned)((j & 7) << 4);
  int smaxAll = (n + 7) >> 3;
  int smin = kk * 16;
  int smax = smaxAll < (kk + 1) * 16 ? smaxAll : (kk + 1) * 16;
  const unsigned* ah2 = (const unsigned*)sAh;
  for (int h = 0; h < 40; ++h) {
    unsigned mm = 0xFBFFFBFFu;               // {-65504, -65504}
    if (j < n) {
      for (int s = smin; s < smax; ++s) {
        u32x4 v = *(const u32x4*)(CT + ((base + (unsigned)(s << 4)) ^ sw));
        unsigned a0 = ah2[s * 4 + 0], a1 = ah2[s * 4 + 1];
        unsigned a2 = ah2[s * 4 + 2], a3 = ah2[s * 4 + 3];
        unsigned t0, t1, t2, t3;
        asm("v_pk_add_f16 %0, %1, %2" : "=v"(t0) : "v"(v[0]), "v"(a0));
        asm("v_pk_add_f16 %0, %1, %2" : "=v"(t1) : "v"(v[1]), "v"(a1));
        asm("v_pk_add_f16 %0, %1, %2" : "=v"(t2) : "v"(v[2]), "v"(a2));
        asm("v_pk_add_f16 %0, %1, %2" : "=v"(t3) : "v"(v[3]), "v"(a3));
        asm("v_pk_max_f16 %0, %0, %1" : "+v"(mm) : "v"(t0));
        asm("v_pk_max_f16 %0, %0, %1" : "+v"(mm) : "v"(t1));
        asm("v_pk_max_f16 %0, %0, %1" : "+v"(mm) : "v"(t2));
        asm("v_pk_max_f16 %0, %0, %1" : "+v"(mm) : "v"(t3));
      }
    }
    sPm[kk * 256 + j] = fmaxf(h2f((unsigned short)(mm & 0xFFFFu)),
                              h2f((unsigned short)(mm >> 16)));
    __syncthreads();
    if (tid < 256) {
      float m2 = fmaxf(sPm[tid], sPm[256 + tid]);
      if (tid < n) {
        ((h & 1) ? sF : sG)[tid] = -EPS_LN2 * m2;
        sAh[tid] = (_Float16)(-log2n - m2);
      }
    }
    __syncthreads();
  }
  if (tid < 64) {
    float a = 0.f;
    for (int i = tid; i < n; i += 64) a += sF[i] + sG[i];
#pragma unroll
    for (int o = 1; o < 64; o <<= 1) a += __shfl_xor(a, o);
    if (tid == 0) Sxx[b] = a / n;
  }
}

// ---------------------------------------------------------------------------
// k_sxy: XY (blocks [0,128)) and YY (blocks [128,256)) Sinkhorn, unchanged.
// ---------------------------------------------------------------------------
#define SK_SMEM 50736

__global__ __launch_bounds__(1024) void k_sxy(
    const float* __restrict__ tr, const float* __restrict__ ir,
    const int* __restrict__ amask,
    float* __restrict__ Sxy, float* __restrict__ Syy) {
  __shared__ __align__(16) char smem[SK_SMEM];
  int role = blockIdx.x >> 7;
  int b    = blockIdx.x & 127;
  int tid  = threadIdx.x;

  if (role == 0) {
    // ====================== XY ======================
    float* Ys  = (float*)smem;                    // [36][64]
    float* Cs  = (float*)(smem + 9216);           // [256][37]
    float* nx  = (float*)(smem + 47104);          // [256]
    float* ny  = (float*)(smem + 48128);          // [36]
    float* sA  = (float*)(smem + 48288);          // padded alpha [272]
    float* sB  = (float*)(smem + 49376);          // beta [36]
    float* sF  = (float*)(smem + 49536);          // [256]
    float* sG  = (float*)(smem + 50560);          // [36]
    int*   nsh = (int*)  (smem + 50720);
    if (tid < 64) {
      int c = 0;
      for (int i = tid; i < 256; i += 64) c += amask[b * 256 + i];
#pragma unroll
      for (int o = 1; o < 64; o <<= 1) c += __shfl_xor(c, o);
      if (tid == 0) *nsh = c;
    }
    const float* Xg = tr + (long)b * 256 * 64;
    const float* Yg = ir + (long)b * 36 * 64;
    for (int idx = tid; idx < 576; idx += 1024) {
      int row = idx >> 4, q4 = idx & 15;
      *(f32x4*)(Ys + row * 64 + q4 * 4) = *(const f32x4*)(Yg + row * 64 + q4 * 4);
    }
    __syncthreads();
    int n = *nsh;
    if (tid < 256) {
      float a = 0.f;
#pragma unroll
      for (int q4 = 0; q4 < 13; ++q4) {
        f32x4 v = *(const f32x4*)(Xg + tid * 64 + q4 * 4);
        a += v[0]*v[0] + v[1]*v[1] + v[2]*v[2] + v[3]*v[3];
      }
      nx[tid] = a;
    } else if (tid < 292) {
      int jj = tid - 256; float a = 0.f;
#pragma unroll
      for (int q4 = 0; q4 < 13; ++q4) {
        f32x4 v = *(const f32x4*)(Ys + jj * 64 + q4 * 4);
        a += v[0]*v[0] + v[1]*v[1] + v[2]*v[2] + v[3]*v[3];
      }
      ny[jj] = a;
    }
    __syncthreads();
    if (tid < 1008) {
      int ii = tid / 36, jj = tid - ii * 36;
      f32x4 yr[13];
#pragma unroll
      for (int q4 = 0; q4 < 13; ++q4) yr[q4] = *(const f32x4*)(Ys + jj * 64 + q4 * 4);
      float nyj = ny[jj];
      for (int i = ii; i < 256; i += 28) {
        float d = 0.f;
#pragma unroll
        for (int q4 = 0; q4 < 13; ++q4) {
          f32x4 xv = *(const f32x4*)(Xg + i * 64 + q4 * 4);
          d += xv[0]*yr[q4][0] + xv[1]*yr[q4][1] + xv[2]*yr[q4][2] + xv[3]*yr[q4][3];
        }
        Cs[i * 37 + jj] = (d - 0.5f * (nx[i] + nyj)) * INV_EPS_LN2;
      }
    }
    __syncthreads();
    int jg = tid >> 4, kg = tid & 15;             // g-role: column jg, slice kg
    float Cg[16];
    if (jg < 36) {
#pragma unroll
      for (int t = 0; t < 16; ++t) Cg[t] = Cs[(kg * 16 + t) * 37 + jg];
    }
    int fi = tid >> 2, kf = tid & 3;              // f-role: row fi, slice kf
    float Cf[9];
#pragma unroll
    for (int t = 0; t < 9; ++t) {
      int jj2 = kf * 9 + t;
      Cf[t] = (jj2 < 36) ? Cs[fi * 37 + jj2] : 0.f;
    }
    float log2n = log2f((float)n);
    if (tid < 256) { sF[tid] = 0.f; sA[tid + (tid >> 4)] = -log2n; }
    __syncthreads();
    const float* agp = sA + kg * 17;
    int gend = n - kg * 16; if (gend > 16) gend = 16;
    for (int it = 0; it < 20; ++it) {
      float gm = -1e30f;
      if (jg < 36) {
#pragma unroll
        for (int t = 0; t < 16; ++t)
          if (t < gend) gm = fmaxf(gm, agp[t] + Cg[t]);
        gm = fmaxf(gm, __shfl_xor(gm, 1)); gm = fmaxf(gm, __shfl_xor(gm, 2));
        gm = fmaxf(gm, __shfl_xor(gm, 4)); gm = fmaxf(gm, __shfl_xor(gm, 8));
      }
      __syncthreads();
      if (jg < 36 && kg == 0) {
        sG[jg] = -EPS_LN2 * gm;
        sB[jg] = -LOG2_36 - gm;
      }
      __syncthreads();
      float fm = -1e30f;
#pragma unroll
      for (int t = 0; t < 9; ++t) {
        int jj2 = kf * 9 + t;
        if (jj2 < 36) fm = fmaxf(fm, sB[jj2] + Cf[t]);
      }
      fm = fmaxf(fm, __shfl_xor(fm, 1)); fm = fmaxf(fm, __shfl_xor(fm, 2));
      __syncthreads();
      if (kf == 0 && fi < n) {
        sF[fi] = -EPS_LN2 * fm;
        sA[fi + (fi >> 4)] = -log2n - fm;
      }
      __syncthreads();
    }
    if (tid < 64) {
      float a = 0.f;
      for (int i = tid; i < n; i += 64) a += sF[i];
      float g = (tid < 36) ? sG[tid] : 0.f;
#pragma unroll
      for (int o = 1; o < 64; o <<= 1) { a += __shfl_xor(a, o); g += __shfl_xor(g, o); }
      if (tid == 0) Sxy[b] = a / n + g / 36.f;
    }
  } else {
    // ====================== YY ======================
    float* Ys = (float*)smem;                     // [36][64]
    float* Cs = (float*)(smem + 9216);            // [36][37]
    float* ny = (float*)(smem + 48128);
    float* sA = (float*)(smem + 48288);           // [36]
    float* sF = (float*)(smem + 49536);
    float* sG = (float*)(smem + 50560);
    const float* Yg = ir + (long)b * 36 * 64;
    for (int idx = tid; idx < 576; idx += 1024) {
      int row = idx >> 4, q4 = idx & 15;
      *(f32x4*)(Ys + row * 64 + q4 * 4) = *(const f32x4*)(Yg + row * 64 + q4 * 4);
    }
    __syncthreads();
    if (tid < 36) {
      float a = 0.f;
#pragma unroll
      for (int q4 = 0; q4 < 13; ++q4) {
        f32x4 v = *(const f32x4*)(Ys + tid * 64 + q4 * 4);
        a += v[0]*v[0] + v[1]*v[1] + v[2]*v[2] + v[3]*v[3];
      }
      ny[tid] = a;
    }
    __syncthreads();
    if (tid < 1008) {
      int ii = tid / 36, jj = tid - ii * 36;
      f32x4 yr[13];
#pragma unroll
      for (int q4 = 0; q4 < 13; ++q4) yr[q4] = *(const f32x4*)(Ys + jj * 64 + q4 * 4);
      float nyj = ny[jj];
      for (int i = ii; i < 36; i += 28) {
        float d = 0.f;
#pragma unroll
        for (int q4 = 0; q4 < 13; ++q4) {
          f32x4 xv = *(const f32x4*)(Ys + i * 64 + q4 * 4);
          d += xv[0]*yr[q4][0] + xv[1]*yr[q4][1] + xv[2]*yr[q4][2] + xv[3]*yr[q4][3];
        }
        Cs[i * 37 + jj] = (d - 0.5f * (ny[i] + nyj)) * INV_EPS_LN2;
      }
    }
    __syncthreads();
    int j = tid >> 2, kk = tid & 3;
    float Creg[9];
    if (j < 36) {
#pragma unroll
      for (int t = 0; t < 9; ++t) {
        int i2 = kk * 9 + t;
        Creg[t] = (i2 < 36) ? Cs[i2 * 37 + j] : 0.f;
      }
    }
    if (tid < 36) { sF[tid] = 0.f; sA[tid] = -LOG2_36; }
    __syncthreads();
    for (int h = 0; h < 40; ++h) {
      float m = -1e30f;
      if (j < 36) {
#pragma unroll
        for (int t = 0; t < 9; ++t) {
          int i2 = kk * 9 + t;
          if (i2 < 36) m = fmaxf(m, sA[i2] + Creg[t]);
        }
        m = fmaxf(m, __shfl_xor(m, 1)); m = fmaxf(m, __shfl_xor(m, 2));
      }
      __syncthreads();
      if (j < 36 && kk == 0) {
        ((h & 1) ? sF : sG)[j] = -EPS_LN2 * m;
        sA[j] = -LOG2_36 - m;
      }
      __syncthreads();
    }
    if (tid < 64) {
      float a = (tid < 36) ? sF[tid] + sG[tid] : 0.f;
#pragma unroll
      for (int o = 1; o < 64; o <<= 1) a += __shfl_xor(a, o);
      if (tid == 0) Syy[b] = a / 36.f;
    }
  }
}

// ---------------------------------------------------------------------------
// Final combine: w_dis -> w_pred, max with mix_pred, 2-way softmax.
// ---------------------------------------------------------------------------
__global__ void k_final(const float* __restrict__ mix, const float* __restrict__ sxy,
                        const float* __restrict__ sxx, const float* __restrict__ syy,
                        float* __restrict__ out) {
  int b = blockIdx.x * 64 + threadIdx.x;
  if (b < 128) {
    float w  = sxy[b] - 0.5f * (sxx[b] + syy[b]);
    float x0 = fmaxf(mix[b * 2 + 0], 1.0f - 0.01f * w);
    float x1 = fmaxf(mix[b * 2 + 1], 0.01f * w);
    float mx = fmaxf(x0, x1);
    float e0 = expf(x0 - mx), e1 = expf(x1 - mx);
    float inv = 1.f / (e0 + e1);
    out[b * 2 + 0] = e0 * inv;
    out[b * 2 + 1] = e1 * inv;
  }
}

// ---------------------------------------------------------------------------
extern "C" void kernel_launch(void* const* d_in, const int* in_sizes, int n_in,
                              void* d_out, int out_size, void* d_ws, size_t ws_size,
                              hipStream_t stream) {
  const float* txt_global = (const float*)d_in[0];
  const float* txt_region = (const float*)d_in[1];
  const float* img_global = (const float*)d_in[2];
  const float* img_region = (const float*)d_in[3];
  const float* social     = (const float*)d_in[4];
  const int*   attn_mask  = (const int*)  d_in[5];
  const float* W_stat = (const float*)d_in[6];  const float* b_stat = (const float*)d_in[7];
  const float* W_gt   = (const float*)d_in[8];  const float* b_gt   = (const float*)d_in[9];
  const float* W_gi   = (const float*)d_in[10]; const float* b_gi   = (const float*)d_in[11];
  const float* W_rt   = (const float*)d_in[12]; const float* b_rt   = (const float*)d_in[13];
  const float* W_ri   = (const float*)d_in[14]; const float* b_ri   = (const float*)d_in[15];
  const float* W_m1   = (const float*)d_in[16]; const float* b_m1   = (const float*)d_in[17];
  const float* W_m2   = (const float*)d_in[18]; const float* b_m2   = (const float*)d_in[19];

  float* ws = (float*)d_ws;
  float* ws_mix = ws;                    // 256
  float* ws_sxy = ws + 256;              // 128
  float* ws_sxx = ws + 384;              // 128
  float* ws_syy = ws + 512;              // 128
  short* ws_frt = (short*)(ws + 1024);   // 49152 shorts -> ends float 25600
  short* ws_fri = (short*)(ws + 25600);  // 131072 shorts -> ends float 91136
  float* ws_tr  = ws + 131072;           // [32768][64]
  float* ws_ir  = ws + 2228224;          // [4608][64]
  float* ws_pre = ws + 2523136;          // [23][128][200]

  k_prep<<<456, 256, 0, stream>>>(W_rt, W_ri, ws_frt, ws_fri,
                                  txt_global, img_global, social,
                                  W_stat, b_stat, W_gt, W_gi, ws_pre);
  k_pm<<<1296, 256, 0, stream>>>(txt_region, ws_frt, b_rt, ws_tr,
                                 img_region, ws_fri, b_ri, ws_ir,
                                 ws_pre, b_gt, b_gi,
                                 W_m1, b_m1, W_m2, b_m2, ws_mix);
  k_sxx<<<128, 512, 0, stream>>>(ws_tr, attn_mask, ws_sxx);
  k_sxy<<<256, 1024, 0, stream>>>(ws_tr, ws_ir, attn_mask, ws_sxy, ws_syy);
  k_final<<<2, 64, 0, stream>>>(ws_mix, ws_sxy, ws_sxx, ws_syy, (float*)d_out);
}

// Round 10
// 359.727 us; speedup vs baseline: 1.1109x; 1.0188x over previous
//
#include <hip/hip_runtime.h>

typedef float        f32x4 __attribute__((ext_vector_type(4)));
typedef short        s16x8 __attribute__((ext_vector_type(8)));
typedef unsigned int u32x4 __attribute__((ext_vector_type(4)));

#define EPS_LN2      0.0017328679513998632f   /* eps*ln2, eps = 0.0025 */
#define INV_EPS_LN2  577.0780163555852f       /* 1/(eps*ln2) */
#define LOG2_36      5.169925001442312f

__device__ __forceinline__ short f2bf(float x) {
  unsigned int u; __builtin_memcpy(&u, &x, 4);
  u = (u + 0x7FFFu + ((u >> 16) & 1u)) >> 16;   // RNE
  return (short)u;
}

__device__ __forceinline__ unsigned short f2h(float x) {
  return __builtin_bit_cast(unsigned short, (_Float16)x);
}
__device__ __forceinline__ float h2f(unsigned short h) {
  return (float)__builtin_bit_cast(_Float16, h);
}

// ---------------------------------------------------------------------------
// k_prep: blocks [0,88) pack W_rt/W_ri into MFMA B-frag order (bf16);
// blocks [88,456) K-split GEMM writing per-job slices pre[23][128][200].
// ---------------------------------------------------------------------------
__global__ __launch_bounds__(256) void k_prep(
    const float* __restrict__ W_rt, const float* __restrict__ W_ri,
    short* __restrict__ frt, short* __restrict__ fri,
    const float* __restrict__ txt, const float* __restrict__ img,
    const float* __restrict__ social,
    const float* __restrict__ W_stat, const float* __restrict__ b_stat,
    const float* __restrict__ W_gt, const float* __restrict__ W_gi,
    float* __restrict__ pre) {
  __shared__ float sA[32][128];
  int bid = blockIdx.x;
  if (bid < 88) {
    int slot = bid * 256 + threadIdx.x;   // 22528 total
    const float* W; short* dst; int f;
    if (slot < 6144) { W = W_rt; dst = frt; f = slot; }
    else             { W = W_ri; dst = fri; f = slot - 6144; }
    int k32 = f >> 8, rem = f & 255, ct = rem >> 6, l = rem & 63;
    int col = ct * 16 + (l & 15);
    int k0  = k32 * 32 + (l >> 4) * 8;
    s16x8 p;
#pragma unroll
    for (int c = 0; c < 8; ++c) {
      float v = (col < 50) ? W[(k0 + c) * 50 + col] : 0.f;
      p[c] = f2bf(v);
    }
    *(s16x8*)(dst + (long)f * 8) = p;
    return;
  }
  int gb = bid - 88;
  int job = gb >> 4, rb = (gb >> 2) & 3, cb = gb & 3;
  int t = threadIdx.x, r0 = rb * 32;
  const float* W; int k0, klen;
  if (job < 6)       { k0 = job * 128;       klen = 128; W = W_gt; }
  else if (job == 6) { k0 = 0;               klen = 100; W = W_gt + 768 * 200; }
  else               { k0 = (job - 7) * 128; klen = 128; W = W_gi; }
  if (job == 6) {
    for (int idx = t; idx < 4096; idx += 256) {
      int r = idx >> 7, k = idx & 127;
      float v = 0.f;
      if (k < 100) {
        v = b_stat[k];
#pragma unroll
        for (int u = 0; u < 10; ++u) v += social[(r0 + r) * 10 + u] * W_stat[u * 100 + k];
        v = fmaxf(v, 0.f);
      }
      sA[r][k] = v;
    }
  } else {
    const float* A = (job < 6) ? txt : img;
    int K_A = (job < 6) ? 768 : 2048;
    for (int idx = t; idx < 4096; idx += 256) {
      int r = idx >> 7, k = idx & 127;
      sA[r][k] = A[(r0 + r) * K_A + k0 + k];
    }
  }
  __syncthreads();
  int c = cb * 64 + (t & 63), rg = t >> 6;
  if (c < 200) {
    float acc[8];
#pragma unroll
    for (int i = 0; i < 8; ++i) acc[i] = 0.f;
    for (int k4 = 0; k4 < klen; k4 += 4) {
      float w0 = W[(k0 + k4    ) * 200 + c];
      float w1 = W[(k0 + k4 + 1) * 200 + c];
      float w2 = W[(k0 + k4 + 2) * 200 + c];
      float w3 = W[(k0 + k4 + 3) * 200 + c];
#pragma unroll
      for (int i = 0; i < 8; ++i) {
        f32x4 a = *(const f32x4*)&sA[rg * 8 + i][k4];
        acc[i] += a[0]*w0 + a[1]*w1 + a[2]*w2 + a[3]*w3;
      }
    }
    float* dst = pre + (long)job * 25600;
#pragma unroll
    for (int i = 0; i < 8; ++i)
      dst[(r0 + rg * 8 + i) * 200 + c] = acc[i];
  }
}

// ---------------------------------------------------------------------------
// Projection GEMM: 3-slot REGISTER ring filled by inline-asm
// global_load_dwordx4 (opaque to the compiler -> it cannot JIT-serialize the
// pipeline or insert conservative vmcnt(0) drains). Counted s_waitcnt
// vmcnt(12) keeps 2 stages (12 loads) in flight per wave; sched_barrier(0)
// fences the consumers (rule #18). No LDS staging; 8KB end-reduce only.
// One block = 32 rows x 2 row-groups x 2 K-halves (4 waves).
// out[M][64] = relu(A[M][K] @ W + bias).
// ---------------------------------------------------------------------------
template<int K32>
__device__ __forceinline__ void proj_body(const float* __restrict__ A,
                                          const short* __restrict__ Bf,
                                          const float* __restrict__ bias,
                                          float* __restrict__ out, int bid,
                                          float* __restrict__ red) {
  constexpr int KH = K32 / 2;               // k32 steps per wave
  int wave = threadIdx.x >> 6, lane = threadIdx.x & 63;
  int rg = wave >> 1, ks = wave & 1;
  int rl = lane & 15, q = lane >> 4;
  int row0 = bid * 32 + rg * 16;
  const int K = K32 * 32;
  const float* ar = A + (long)(row0 + rl) * K + ks * (KH * 32) + q * 8;
  const s16x8* bp = (const s16x8*)Bf + ks * (KH * 256) + lane;

  f32x4 pa0[3], pa1[3];
  s16x8 pb0[3], pb1[3], pb2[3], pb3[3];

#define GLF(D, P) asm volatile("global_load_dwordx4 %0, %1, off" \
                               : "=&v"(D) : "v"(P) : "memory")
#define ISSUE(KK, S) { \
    const float* ap_ = ar + (KK) * 32; \
    GLF(pa0[S], ap_); GLF(pa1[S], ap_ + 4); \
    const s16x8* bp_ = bp + (KK) * 256; \
    GLF(pb0[S], bp_); GLF(pb1[S], bp_ + 64); \
    GLF(pb2[S], bp_ + 128); GLF(pb3[S], bp_ + 192); }

  f32x4 acc[4];
#pragma unroll
  for (int ct = 0; ct < 4; ++ct) acc[ct] = (f32x4){0.f, 0.f, 0.f, 0.f};

  ISSUE(0, 0);
  ISSUE(1, 1);
#pragma unroll
  for (int k = 0; k < KH; ++k) {
    if (k + 2 < KH) {
      ISSUE(k + 2, (k + 2) % 3);
      asm volatile("s_waitcnt vmcnt(12)" ::: "memory");  // slot k landed
    } else if (k + 2 == KH) {
      asm volatile("s_waitcnt vmcnt(6)" ::: "memory");
    } else {
      asm volatile("s_waitcnt vmcnt(0)" ::: "memory");
    }
    __builtin_amdgcn_sched_barrier(0);
    int s = k % 3;                          // compile-time after unroll
    s16x8 af;
    af[0]=f2bf(pa0[s][0]); af[1]=f2bf(pa0[s][1]);
    af[2]=f2bf(pa0[s][2]); af[3]=f2bf(pa0[s][3]);
    af[4]=f2bf(pa1[s][0]); af[5]=f2bf(pa1[s][1]);
    af[6]=f2bf(pa1[s][2]); af[7]=f2bf(pa1[s][3]);
    acc[0] = __builtin_amdgcn_mfma_f32_16x16x32_bf16(af, pb0[s], acc[0], 0, 0, 0);
    acc[1] = __builtin_amdgcn_mfma_f32_16x16x32_bf16(af, pb1[s], acc[1], 0, 0, 0);
    acc[2] = __builtin_amdgcn_mfma_f32_16x16x32_bf16(af, pb2[s], acc[2], 0, 0, 0);
    acc[3] = __builtin_amdgcn_mfma_f32_16x16x32_bf16(af, pb3[s], acc[3], 0, 0, 0);
  }
#undef ISSUE
#undef GLF

  // ---- K-split reduce: ks=1 dumps partials, ks=0 combines + writes ----
  float* rb = red + rg * 1024;              // [64][16] per row-group
  if (ks == 1) {
#pragma unroll
    for (int ct = 0; ct < 4; ++ct)
      *(f32x4*)(rb + lane * 16 + ct * 4) = acc[ct];
  }
  __syncthreads();
  if (ks == 0) {
#pragma unroll
    for (int ct = 0; ct < 4; ++ct) {
      f32x4 o = *(const f32x4*)(rb + lane * 16 + ct * 4);
      int col = ct * 16 + rl;
      float bv = (col < 50) ? bias[col] : 0.f;
#pragma unroll
      for (int r = 0; r < 4; ++r) {
        int grow = row0 + q * 4 + r;         // D row = quad*4+reg (m89)
        float v = fmaxf(acc[ct][r] + o[r] + bv, 0.f);
        out[(long)grow * 64 + col] = (col < 50) ? v : 0.f;
      }
    }
  }
}

// MLP tail body: one block per batch row; sums the 23 per-job GEMM slices.
__device__ __forceinline__ void mix_body(
    int r, const float* __restrict__ pre,
    const float* __restrict__ b_gt, const float* __restrict__ b_gi,
    const float* __restrict__ W_m1, const float* __restrict__ b_m1,
    const float* __restrict__ W_m2, const float* __restrict__ b_m2,
    float* __restrict__ mix, float* smem) {
  float* sm = smem;            // [200]
  float* sh = smem + 200;      // [100]
  int t = threadIdx.x;
  if (t < 200) {
    float s1 = b_gt[t], s2 = b_gi[t];
#pragma unroll
    for (int j = 0; j < 7; ++j)  s1 += pre[(long)j * 25600 + r * 200 + t];
#pragma unroll
    for (int j = 7; j < 23; ++j) s2 += pre[(long)j * 25600 + r * 200 + t];
    sm[t] = fmaxf(s1, 0.f) + fmaxf(s2, 0.f);
  }
  __syncthreads();
  if (t < 100) {
    float a = b_m1[t];
#pragma unroll 4
    for (int k = 0; k < 200; ++k) a += sm[k] * W_m1[k * 100 + t];
    sh[t] = fmaxf(a, 0.f);
  }
  __syncthreads();
  if (t < 2) {
    float a = b_m2[t];
    for (int k = 0; k < 100; ++k) a += sh[k] * W_m2[k * 2 + t];
    mix[r * 2 + t] = a;
  }
}

// Grid order: img proj [0,144) first (longest: 32 steps/wave), txt proj
// [144,1168), mix [1168,1296) last (tiny).
__global__ __launch_bounds__(256)
void k_pm(
    const float* __restrict__ txt_region, const short* __restrict__ frt,
    const float* __restrict__ b_rt, float* __restrict__ tr,
    const float* __restrict__ img_region, const short* __restrict__ fri,
    const float* __restrict__ b_ri, float* __restrict__ ir,
    const float* __restrict__ pre,
    const float* __restrict__ b_gt, const float* __restrict__ b_gi,
    const float* __restrict__ W_m1, const float* __restrict__ b_m1,
    const float* __restrict__ W_m2, const float* __restrict__ b_m2,
    float* __restrict__ mix) {
  __shared__ __align__(16) float red[2048];   // 8 KB reduce / mix scratch
  int bid = blockIdx.x;
  if (bid < 144)       proj_body<64>(img_region, fri, b_ri, ir, bid, red);
  else if (bid < 1168) proj_body<24>(txt_region, frt, b_rt, tr, bid - 144, red);
  else                 mix_body(bid - 1168, pre, b_gt, b_gi, W_m1, b_m1, W_m2, b_m2, mix, red);
}

// ---------------------------------------------------------------------------
// k_sxx: XX Sinkhorn, 512 threads (8 waves). Column j = tid&255, i-groups
// stride-2 interleaved across kk = tid>>8 (balanced for any n), trip count
// tmax = ceil(n/16), partial unroll 4 -> 4 independent ds_read_b128 in
// flight (round 9's runtime-bounded loop serialized into 16x120cy chains:
// VALUBusy 8%, 81us). CT swizzle mask widened (j&7 -> j&31): all 32 16B
// slots/row distinct across a half-wave -> 2-way aliasing only (free),
// vs measured 1M bank-conflict cycles with the 8-way (j&7) version.
// Reads past n are safe: CT fully written & finite; alpha[i>=n] = -65504
// forever, so padded terms never win the max (f16 -inf on underflow is a
// legal max loser).
// ---------------------------------------------------------------------------
__global__ __launch_bounds__(512) void k_sxx(
    const float* __restrict__ tr, const int* __restrict__ amask,
    float* __restrict__ Sxx) {
  __shared__ __align__(16) char smem[163840];
  char*  CT    = smem;                       // f16 CT[256][512B] XOR-swz
  float* norms = (float*)smem;               // temp, inside CT region
  short* Xf    = (short*)(smem + 131072);    // 32 KB, dead after MFMA phase
  float*     sPm = (float*)(smem + 131072);  // [2][256] aliases Xf
  float*     sF  = (float*)(smem + 133120);
  float*     sG  = (float*)(smem + 134144);
  _Float16*  sAh = (_Float16*)(smem + 135168);
  int b = blockIdx.x, tid = threadIdx.x;
  int lane = tid & 63, wv = tid >> 6;
  int q = lane >> 4, rl = lane & 15;

  // ---- n: per-wave reduce ----
  int c = 0;
#pragma unroll
  for (int i = 0; i < 4; ++i) c += amask[b * 256 + i * 64 + lane];
#pragma unroll
  for (int o = 1; o < 64; o <<= 1) c += __shfl_xor(c, o);
  int n = __builtin_amdgcn_readfirstlane(c);

  // ---- stage Xf (bf16 MFMA frags of X) ----
  const float* Xg = tr + (long)b * 256 * 64;
  for (int slot = tid; slot < 2048; slot += 512) {
    int t = slot >> 7, k32 = (slot >> 6) & 1, l = slot & 63;
    int row = t * 16 + (l & 15), k0 = k32 * 32 + (l >> 4) * 8;
    const float* src = Xg + row * 64 + k0;
    f32x4 a0 = *(const f32x4*)src, a1 = *(const f32x4*)(src + 4);
    s16x8 p;
    p[0]=f2bf(a0[0]); p[1]=f2bf(a0[1]); p[2]=f2bf(a0[2]); p[3]=f2bf(a0[3]);
    p[4]=f2bf(a1[0]); p[5]=f2bf(a1[1]); p[6]=f2bf(a1[2]); p[7]=f2bf(a1[3]);
    *(s16x8*)(Xf + slot * 8) = p;
  }
  __syncthreads();

  // ---- phase 1: diag tiles -> norms (in CT region, not yet written) ----
#pragma unroll
  for (int si = 0; si < 2; ++si) {
    int st = wv * 2 + si;
    s16x8 a0 = *(const s16x8*)(Xf + ((st * 2 + 0) * 64 + lane) * 8);
    s16x8 a1 = *(const s16x8*)(Xf + ((st * 2 + 1) * 64 + lane) * 8);
    f32x4 d = (f32x4){0.f, 0.f, 0.f, 0.f};
    d = __builtin_amdgcn_mfma_f32_16x16x32_bf16(a0, a0, d, 0, 0, 0);
    d = __builtin_amdgcn_mfma_f32_16x16x32_bf16(a1, a1, d, 0, 0, 0);
#pragma unroll
    for (int r = 0; r < 4; ++r)
      if (rl == q * 4 + r) norms[st * 16 + q * 4 + r] = d[r];
  }
  __syncthreads();

  // preload ALL norms this thread needs into registers, then barrier so
  // phase-2 CT writes can safely clobber the norms slice.
  float nj[16];
#pragma unroll
  for (int ct = 0; ct < 16; ++ct) nj[ct] = norms[ct * 16 + rl];
  float ni[2][4];
#pragma unroll
  for (int si = 0; si < 2; ++si) {
    int base = (wv * 2 + si) * 16 + q * 4;
#pragma unroll
    for (int r = 0; r < 4; ++r) ni[si][r] = norms[base + r];
  }
  __syncthreads();

  // ---- phase 2: full tiles per strip; write CT[j][i] f16 swizzled ----
#pragma unroll
  for (int si = 0; si < 2; ++si) {
    int st = wv * 2 + si;
    int i0w = st * 16 + q * 4;
    s16x8 a0 = *(const s16x8*)(Xf + ((st * 2 + 0) * 64 + lane) * 8);
    s16x8 a1 = *(const s16x8*)(Xf + ((st * 2 + 1) * 64 + lane) * 8);
    f32x4 acc[16];
#pragma unroll
    for (int ct = 0; ct < 16; ++ct) acc[ct] = (f32x4){0.f, 0.f, 0.f, 0.f};
#pragma unroll
    for (int ct = 0; ct < 16; ++ct) {
      s16x8 b0 = *(const s16x8*)(Xf + ((ct * 2 + 0) * 64 + lane) * 8);
      s16x8 b1 = *(const s16x8*)(Xf + ((ct * 2 + 1) * 64 + lane) * 8);
      acc[ct] = __builtin_amdgcn_mfma_f32_16x16x32_bf16(a0, b0, acc[ct], 0, 0, 0);
      acc[ct] = __builtin_amdgcn_mfma_f32_16x16x32_bf16(a1, b1, acc[ct], 0, 0, 0);
    }
#pragma unroll
    for (int ct = 0; ct < 16; ++ct) {
      int j = ct * 16 + rl;
      float njv = nj[ct];
      float v0 = (acc[ct][0] - 0.5f * (ni[si][0] + njv)) * INV_EPS_LN2;
      float v1 = (acc[ct][1] - 0.5f * (ni[si][1] + njv)) * INV_EPS_LN2;
      float v2 = (acc[ct][2] - 0.5f * (ni[si][2] + njv)) * INV_EPS_LN2;
      float v3 = (acc[ct][3] - 0.5f * (ni[si][3] + njv)) * INV_EPS_LN2;
      char* p = CT + (((j << 9) + (i0w << 1)) ^ ((j & 31) << 4));
      *(unsigned*)(p)     = (unsigned)f2h(v0) | ((unsigned)f2h(v1) << 16);
      *(unsigned*)(p + 4) = (unsigned)f2h(v2) | ((unsigned)f2h(v3) << 16);
    }
  }
  __syncthreads();                           // Xf dead; CT complete

  // ---- init loop state (aliases Xf region) ----
  float log2n = log2f((float)n);
  if (tid < 256) {
    sF[tid] = 0.f; sG[tid] = 0.f;
    sAh[tid] = (tid < n) ? (_Float16)(-log2n) : (_Float16)(-65504.f);
  }
  __syncthreads();

  // ---- 40 max-plus half-steps: column j, stride-2 kk split, unroll 4 ----
  int kk = tid >> 8, j = tid & 255;
  unsigned base = (unsigned)(j << 9);
  unsigned sw   = (unsigned)((j & 31) << 4);
  int tmax = (n + 15) >> 4;                  // ceil(n/16); s = 2t+kk <= 31
  const char* aB = (const char*)sAh;
  for (int h = 0; h < 40; ++h) {
    unsigned mm = 0xFBFFFBFFu;               // {-65504, -65504}
#pragma unroll 4
    for (int t = 0; t < tmax; ++t) {
      int s = 2 * t + kk;
      u32x4 v  = *(const u32x4*)(CT + ((base + (unsigned)(s << 4)) ^ sw));
      u32x4 av = *(const u32x4*)(aB + s * 16);     // broadcast (uniform addr)
      unsigned t0, t1, t2, t3;
      asm("v_pk_add_f16 %0, %1, %2" : "=v"(t0) : "v"(v[0]), "v"(av[0]));
      asm("v_pk_add_f16 %0, %1, %2" : "=v"(t1) : "v"(v[1]), "v"(av[1]));
      asm("v_pk_add_f16 %0, %1, %2" : "=v"(t2) : "v"(v[2]), "v"(av[2]));
      asm("v_pk_add_f16 %0, %1, %2" : "=v"(t3) : "v"(v[3]), "v"(av[3]));
      asm("v_pk_max_f16 %0, %0, %1" : "+v"(mm) : "v"(t0));
      asm("v_pk_max_f16 %0, %0, %1" : "+v"(mm) : "v"(t1));
      asm("v_pk_max_f16 %0, %0, %1" : "+v"(mm) : "v"(t2));
      asm("v_pk_max_f16 %0, %0, %1" : "+v"(mm) : "v"(t3));
    }
    sPm[kk * 256 + j] = fmaxf(h2f((unsigned short)(mm & 0xFFFFu)),
                              h2f((unsigned short)(mm >> 16)));
    __syncthreads();
    if (tid < 256) {
      float m2 = fmaxf(sPm[tid], sPm[256 + tid]);
      if (tid < n) {
        ((h & 1) ? sF : sG)[tid] = -EPS_LN2 * m2;
        sAh[tid] = (_Float16)(-log2n - m2);
      }
    }
    __syncthreads();
  }
  if (tid < 64) {
    float a = 0.f;
    for (int i = tid; i < n; i += 64) a += sF[i] + sG[i];
#pragma unroll
    for (int o = 1; o < 64; o <<= 1) a += __shfl_xor(a, o);
    if (tid == 0) Sxx[b] = a / n;
  }
}

// ---------------------------------------------------------------------------
// k_sxy: XY (blocks [0,128)) and YY (blocks [128,256)) Sinkhorn, unchanged.
// ---------------------------------------------------------------------------
#define SK_SMEM 50736

__global__ __launch_bounds__(1024) void k_sxy(
    const float* __restrict__ tr, const float* __restrict__ ir,
    const int* __restrict__ amask,
    float* __restrict__ Sxy, float* __restrict__ Syy) {
  __shared__ __align__(16) char smem[SK_SMEM];
  int role = blockIdx.x >> 7;
  int b    = blockIdx.x & 127;
  int tid  = threadIdx.x;

  if (role == 0) {
    // ====================== XY ======================
    float* Ys  = (float*)smem;                    // [36][64]
    float* Cs  = (float*)(smem + 9216);           // [256][37]
    float* nx  = (float*)(smem + 47104);          // [256]
    float* ny  = (float*)(smem + 48128);          // [36]
    float* sA  = (float*)(smem + 48288);          // padded alpha [272]
    float* sB  = (float*)(smem + 49376);          // beta [36]
    float* sF  = (float*)(smem + 49536);          // [256]
    float* sG  = (float*)(smem + 50560);          // [36]
    int*   nsh = (int*)  (smem + 50720);
    if (tid < 64) {
      int c = 0;
      for (int i = tid; i < 256; i += 64) c += amask[b * 256 + i];
#pragma unroll
      for (int o = 1; o < 64; o <<= 1) c += __shfl_xor(c, o);
      if (tid == 0) *nsh = c;
    }
    const float* Xg = tr + (long)b * 256 * 64;
    const float* Yg = ir + (long)b * 36 * 64;
    for (int idx = tid; idx < 576; idx += 1024) {
      int row = idx >> 4, q4 = idx & 15;
      *(f32x4*)(Ys + row * 64 + q4 * 4) = *(const f32x4*)(Yg + row * 64 + q4 * 4);
    }
    __syncthreads();
    int n = *nsh;
    if (tid < 256) {
      float a = 0.f;
#pragma unroll
      for (int q4 = 0; q4 < 13; ++q4) {
        f32x4 v = *(const f32x4*)(Xg + tid * 64 + q4 * 4);
        a += v[0]*v[0] + v[1]*v[1] + v[2]*v[2] + v[3]*v[3];
      }
      nx[tid] = a;
    } else if (tid < 292) {
      int jj = tid - 256; float a = 0.f;
#pragma unroll
      for (int q4 = 0; q4 < 13; ++q4) {
        f32x4 v = *(const f32x4*)(Ys + jj * 64 + q4 * 4);
        a += v[0]*v[0] + v[1]*v[1] + v[2]*v[2] + v[3]*v[3];
      }
      ny[jj] = a;
    }
    __syncthreads();
    if (tid < 1008) {
      int ii = tid / 36, jj = tid - ii * 36;
      f32x4 yr[13];
#pragma unroll
      for (int q4 = 0; q4 < 13; ++q4) yr[q4] = *(const f32x4*)(Ys + jj * 64 + q4 * 4);
      float nyj = ny[jj];
      for (int i = ii; i < 256; i += 28) {
        float d = 0.f;
#pragma unroll
        for (int q4 = 0; q4 < 13; ++q4) {
          f32x4 xv = *(const f32x4*)(Xg + i * 64 + q4 * 4);
          d += xv[0]*yr[q4][0] + xv[1]*yr[q4][1] + xv[2]*yr[q4][2] + xv[3]*yr[q4][3];
        }
        Cs[i * 37 + jj] = (d - 0.5f * (nx[i] + nyj)) * INV_EPS_LN2;
      }
    }
    __syncthreads();
    int jg = tid >> 4, kg = tid & 15;             // g-role: column jg, slice kg
    float Cg[16];
    if (jg < 36) {
#pragma unroll
      for (int t = 0; t < 16; ++t) Cg[t] = Cs[(kg * 16 + t) * 37 + jg];
    }
    int fi = tid >> 2, kf = tid & 3;              // f-role: row fi, slice kf
    float Cf[9];
#pragma unroll
    for (int t = 0; t < 9; ++t) {
      int jj2 = kf * 9 + t;
      Cf[t] = (jj2 < 36) ? Cs[fi * 37 + jj2] : 0.f;
    }
    float log2n = log2f((float)n);
    if (tid < 256) { sF[tid] = 0.f; sA[tid + (tid >> 4)] = -log2n; }
    __syncthreads();
    const float* agp = sA + kg * 17;
    int gend = n - kg * 16; if (gend > 16) gend = 16;
    for (int it = 0; it < 20; ++it) {
      float gm = -1e30f;
      if (jg < 36) {
#pragma unroll
        for (int t = 0; t < 16; ++t)
          if (t < gend) gm = fmaxf(gm, agp[t] + Cg[t]);
        gm = fmaxf(gm, __shfl_xor(gm, 1)); gm = fmaxf(gm, __shfl_xor(gm, 2));
        gm = fmaxf(gm, __shfl_xor(gm, 4)); gm = fmaxf(gm, __shfl_xor(gm, 8));
      }
      __syncthreads();
      if (jg < 36 && kg == 0) {
        sG[jg] = -EPS_LN2 * gm;
        sB[jg] = -LOG2_36 - gm;
      }
      __syncthreads();
      float fm = -1e30f;
#pragma unroll
      for (int t = 0; t < 9; ++t) {
        int jj2 = kf * 9 + t;
        if (jj2 < 36) fm = fmaxf(fm, sB[jj2] + Cf[t]);
      }
      fm = fmaxf(fm, __shfl_xor(fm, 1)); fm = fmaxf(fm, __shfl_xor(fm, 2));
      __syncthreads();
      if (kf == 0 && fi < n) {
        sF[fi] = -EPS_LN2 * fm;
        sA[fi + (fi >> 4)] = -log2n - fm;
      }
      __syncthreads();
    }
    if (tid < 64) {
      float a = 0.f;
      for (int i = tid; i < n; i += 64) a += sF[i];
      float g = (tid < 36) ? sG[tid] : 0.f;
#pragma unroll
      for (int o = 1; o < 64; o <<= 1) { a += __shfl_xor(a, o); g += __shfl_xor(g, o); }
      if (tid == 0) Sxy[b] = a / n + g / 36.f;
    }
  } else {
    // ====================== YY ======================
    float* Ys = (float*)smem;                     // [36][64]
    float* Cs = (float*)(smem + 9216);            // [36][37]
    float* ny = (float*)(smem + 48128);
    float* sA = (float*)(smem + 48288);           // [36]
    float* sF = (float*)(smem + 49536);
    float* sG = (float*)(smem + 50560);
    const float* Yg = ir + (long)b * 36 * 64;
    for (int idx = tid; idx < 576; idx += 1024) {
      int row = idx >> 4, q4 = idx & 15;
      *(f32x4*)(Ys + row * 64 + q4 * 4) = *(const f32x4*)(Yg + row * 64 + q4 * 4);
    }
    __syncthreads();
    if (tid < 36) {
      float a = 0.f;
#pragma unroll
      for (int q4 = 0; q4 < 13; ++q4) {
        f32x4 v = *(const f32x4*)(Ys + tid * 64 + q4 * 4);
        a += v[0]*v[0] + v[1]*v[1] + v[2]*v[2] + v[3]*v[3];
      }
      ny[tid] = a;
    }
    __syncthreads();
    if (tid < 1008) {
      int ii = tid / 36, jj = tid - ii * 36;
      f32x4 yr[13];
#pragma unroll
      for (int q4 = 0; q4 < 13; ++q4) yr[q4] = *(const f32x4*)(Ys + jj * 64 + q4 * 4);
      float nyj = ny[jj];
      for (int i = ii; i < 36; i += 28) {
        float d = 0.f;
#pragma unroll
        for (int q4 = 0; q4 < 13; ++q4) {
          f32x4 xv = *(const f32x4*)(Ys + i * 64 + q4 * 4);
          d += xv[0]*yr[q4][0] + xv[1]*yr[q4][1] + xv[2]*yr[q4][2] + xv[3]*yr[q4][3];
        }
        Cs[i * 37 + jj] = (d - 0.5f * (ny[i] + nyj)) * INV_EPS_LN2;
      }
    }
    __syncthreads();
    int j = tid >> 2, kk = tid & 3;
    float Creg[9];
    if (j < 36) {
#pragma unroll
      for (int t = 0; t < 9; ++t) {
        int i2 = kk * 9 + t;
        Creg[t] = (i2 < 36) ? Cs[i2 * 37 + j] : 0.f;
      }
    }
    if (tid < 36) { sF[tid] = 0.f; sA[tid] = -LOG2_36; }
    __syncthreads();
    for (int h = 0; h < 40; ++h) {
      float m = -1e30f;
      if (j < 36) {
#pragma unroll
        for (int t = 0; t < 9; ++t) {
          int i2 = kk * 9 + t;
          if (i2 < 36) m = fmaxf(m, sA[i2] + Creg[t]);
        }
        m = fmaxf(m, __shfl_xor(m, 1)); m = fmaxf(m, __shfl_xor(m, 2));
      }
      __syncthreads();
      if (j < 36 && kk == 0) {
        ((h & 1) ? sF : sG)[j] = -EPS_LN2 * m;
        sA[j] = -LOG2_36 - m;
      }
      __syncthreads();
    }
    if (tid < 64) {
      float a = (tid < 36) ? sF[tid] + sG[tid] : 0.f;
#pragma unroll
      for (int o = 1; o < 64; o <<= 1) a += __shfl_xor(a, o);
      if (tid == 0) Syy[b] = a / 36.f;
    }
  }
}

// ---------------------------------------------------------------------------
// Final combine: w_dis -> w_pred, max with mix_pred, 2-way softmax.
// ---------------------------------------------------------------------------
__global__ void k_final(const float* __restrict__ mix, const float* __restrict__ sxy,
                        const float* __restrict__ sxx, const float* __restrict__ syy,
                        float* __restrict__ out) {
  int b = blockIdx.x * 64 + threadIdx.x;
  if (b < 128) {
    float w  = sxy[b] - 0.5f * (sxx[b] + syy[b]);
    float x0 = fmaxf(mix[b * 2 + 0], 1.0f - 0.01f * w);
    float x1 = fmaxf(mix[b * 2 + 1], 0.01f * w);
    float mx = fmaxf(x0, x1);
    float e0 = expf(x0 - mx), e1 = expf(x1 - mx);
    float inv = 1.f / (e0 + e1);
    out[b * 2 + 0] = e0 * inv;
    out[b * 2 + 1] = e1 * inv;
  }
}

// ---------------------------------------------------------------------------
extern "C" void kernel_launch(void* const* d_in, const int* in_sizes, int n_in,
                              void* d_out, int out_size, void* d_ws, size_t ws_size,
                              hipStream_t stream) {
  const float* txt_global = (const float*)d_in[0];
  const float* txt_region = (const float*)d_in[1];
  const float* img_global = (const float*)d_in[2];
  const float* img_region = (const float*)d_in[3];
  const float* social     = (const float*)d_in[4];
  const int*   attn_mask  = (const int*)  d_in[5];
  const float* W_stat = (const float*)d_in[6];  const float* b_stat = (const float*)d_in[7];
  const float* W_gt   = (const float*)d_in[8];  const float* b_gt   = (const float*)d_in[9];
  const float* W_gi   = (const float*)d_in[10]; const float* b_gi   = (const float*)d_in[11];
  const float* W_rt   = (const float*)d_in[12]; const float* b_rt   = (const float*)d_in[13];
  const float* W_ri   = (const float*)d_in[14]; const float* b_ri   = (const float*)d_in[15];
  const float* W_m1   = (const float*)d_in[16]; const float* b_m1   = (const float*)d_in[17];
  const float* W_m2   = (const float*)d_in[18]; const float* b_m2   = (const float*)d_in[19];

  float* ws = (float*)d_ws;
  float* ws_mix = ws;                    // 256
  float* ws_sxy = ws + 256;              // 128
  float* ws_sxx = ws + 384;              // 128
  float* ws_syy = ws + 512;              // 128
  short* ws_frt = (short*)(ws + 1024);   // 49152 shorts -> ends float 25600
  short* ws_fri = (short*)(ws + 25600);  // 131072 shorts -> ends float 91136
  float* ws_tr  = ws + 131072;           // [32768][64]
  float* ws_ir  = ws + 2228224;          // [4608][64]
  float* ws_pre = ws + 2523136;          // [23][128][200]

  k_prep<<<456, 256, 0, stream>>>(W_rt, W_ri, ws_frt, ws_fri,
                                  txt_global, img_global, social,
                                  W_stat, b_stat, W_gt, W_gi, ws_pre);
  k_pm<<<1296, 256, 0, stream>>>(txt_region, ws_frt, b_rt, ws_tr,
                                 img_region, ws_fri, b_ri, ws_ir,
                                 ws_pre, b_gt, b_gi,
                                 W_m1, b_m1, W_m2, b_m2, ws_mix);
  k_sxx<<<128, 512, 0, stream>>>(ws_tr, attn_mask, ws_sxx);
  k_sxy<<<256, 1024, 0, stream>>>(ws_tr, ws_ir, attn_mask, ws_sxy, ws_syy);
  k_final<<<2, 64, 0, stream>>>(ws_mix, ws_sxy, ws_sxx, ws_syy, (float*)d_out);
}

// Round 11
// 359.620 us; speedup vs baseline: 1.1113x; 1.0003x over previous
//
#include <hip/hip_runtime.h>

typedef float        f32x4 __attribute__((ext_vector_type(4)));
typedef short        s16x8 __attribute__((ext_vector_type(8)));
typedef unsigned int u32x4 __attribute__((ext_vector_type(4)));

#define EPS_LN2      0.0017328679513998632f   /* eps*ln2, eps = 0.0025 */
#define INV_EPS_LN2  577.0780163555852f       /* 1/(eps*ln2) */
#define LOG2_36      5.169925001442312f

__device__ __forceinline__ short f2bf(float x) {
  unsigned int u; __builtin_memcpy(&u, &x, 4);
  u = (u + 0x7FFFu + ((u >> 16) & 1u)) >> 16;   // RNE
  return (short)u;
}

__device__ __forceinline__ unsigned short f2h(float x) {
  return __builtin_bit_cast(unsigned short, (_Float16)x);
}
__device__ __forceinline__ float h2f(unsigned short h) {
  return (float)__builtin_bit_cast(_Float16, h);
}

// ---------------------------------------------------------------------------
// k_prep: blocks [0,88) pack W_rt/W_ri into MFMA B-frag order (bf16);
// blocks [88,456) K-split GEMM writing per-job slices pre[23][128][200].
// ---------------------------------------------------------------------------
__global__ __launch_bounds__(256) void k_prep(
    const float* __restrict__ W_rt, const float* __restrict__ W_ri,
    short* __restrict__ frt, short* __restrict__ fri,
    const float* __restrict__ txt, const float* __restrict__ img,
    const float* __restrict__ social,
    const float* __restrict__ W_stat, const float* __restrict__ b_stat,
    const float* __restrict__ W_gt, const float* __restrict__ W_gi,
    float* __restrict__ pre) {
  __shared__ float sA[32][128];
  int bid = blockIdx.x;
  if (bid < 88) {
    int slot = bid * 256 + threadIdx.x;   // 22528 total
    const float* W; short* dst; int f;
    if (slot < 6144) { W = W_rt; dst = frt; f = slot; }
    else             { W = W_ri; dst = fri; f = slot - 6144; }
    int k32 = f >> 8, rem = f & 255, ct = rem >> 6, l = rem & 63;
    int col = ct * 16 + (l & 15);
    int k0  = k32 * 32 + (l >> 4) * 8;
    s16x8 p;
#pragma unroll
    for (int c = 0; c < 8; ++c) {
      float v = (col < 50) ? W[(k0 + c) * 50 + col] : 0.f;
      p[c] = f2bf(v);
    }
    *(s16x8*)(dst + (long)f * 8) = p;
    return;
  }
  int gb = bid - 88;
  int job = gb >> 4, rb = (gb >> 2) & 3, cb = gb & 3;
  int t = threadIdx.x, r0 = rb * 32;
  const float* W; int k0, klen;
  if (job < 6)       { k0 = job * 128;       klen = 128; W = W_gt; }
  else if (job == 6) { k0 = 0;               klen = 100; W = W_gt + 768 * 200; }
  else               { k0 = (job - 7) * 128; klen = 128; W = W_gi; }
  if (job == 6) {
    for (int idx = t; idx < 4096; idx += 256) {
      int r = idx >> 7, k = idx & 127;
      float v = 0.f;
      if (k < 100) {
        v = b_stat[k];
#pragma unroll
        for (int u = 0; u < 10; ++u) v += social[(r0 + r) * 10 + u] * W_stat[u * 100 + k];
        v = fmaxf(v, 0.f);
      }
      sA[r][k] = v;
    }
  } else {
    const float* A = (job < 6) ? txt : img;
    int K_A = (job < 6) ? 768 : 2048;
    for (int idx = t; idx < 4096; idx += 256) {
      int r = idx >> 7, k = idx & 127;
      sA[r][k] = A[(r0 + r) * K_A + k0 + k];
    }
  }
  __syncthreads();
  int c = cb * 64 + (t & 63), rg = t >> 6;
  if (c < 200) {
    float acc[8];
#pragma unroll
    for (int i = 0; i < 8; ++i) acc[i] = 0.f;
    for (int k4 = 0; k4 < klen; k4 += 4) {
      float w0 = W[(k0 + k4    ) * 200 + c];
      float w1 = W[(k0 + k4 + 1) * 200 + c];
      float w2 = W[(k0 + k4 + 2) * 200 + c];
      float w3 = W[(k0 + k4 + 3) * 200 + c];
#pragma unroll
      for (int i = 0; i < 8; ++i) {
        f32x4 a = *(const f32x4*)&sA[rg * 8 + i][k4];
        acc[i] += a[0]*w0 + a[1]*w1 + a[2]*w2 + a[3]*w3;
      }
    }
    float* dst = pre + (long)job * 25600;
#pragma unroll
    for (int i = 0; i < 8; ++i)
      dst[(r0 + rg * 8 + i) * 200 + c] = acc[i];
  }
}

// ---------------------------------------------------------------------------
// Projection GEMM: 3-slot REGISTER ring filled by inline-asm
// global_load_dwordx4. Ring liveness is ~100 VGPR (24/stage x 3 stages +
// 16 acc + addrs); round 10 showed VGPR_Count=64 -> the default occupancy
// target forced the allocator to SPILL the ring to scratch (scratch ops
// count in vmcnt -> the counted vmcnt(12) broke -> serial 650cy/step).
// amdgpu_waves_per_eu(2,4) raises the budget to 128 VGPR: zero spill, the
// 12-deep pipeline materializes. Counted s_waitcnt vmcnt(12) keeps 2
// stages in flight; sched_barrier(0) fences consumers (rule #18).
// One block = 32 rows x 2 row-groups x 2 K-halves (4 waves).
// out[M][64] = relu(A[M][K] @ W + bias).
// ---------------------------------------------------------------------------
template<int K32>
__device__ __forceinline__ void proj_body(const float* __restrict__ A,
                                          const short* __restrict__ Bf,
                                          const float* __restrict__ bias,
                                          float* __restrict__ out, int bid,
                                          float* __restrict__ red) {
  constexpr int KH = K32 / 2;               // k32 steps per wave
  int wave = threadIdx.x >> 6, lane = threadIdx.x & 63;
  int rg = wave >> 1, ks = wave & 1;
  int rl = lane & 15, q = lane >> 4;
  int row0 = bid * 32 + rg * 16;
  const int K = K32 * 32;
  const float* ar = A + (long)(row0 + rl) * K + ks * (KH * 32) + q * 8;
  const s16x8* bp = (const s16x8*)Bf + ks * (KH * 256) + lane;

  f32x4 pa0[3], pa1[3];
  s16x8 pb0[3], pb1[3], pb2[3], pb3[3];

#define GLF(D, P) asm volatile("global_load_dwordx4 %0, %1, off" \
                               : "=&v"(D) : "v"(P) : "memory")
#define ISSUE(KK, S) { \
    const float* ap_ = ar + (KK) * 32; \
    GLF(pa0[S], ap_); GLF(pa1[S], ap_ + 4); \
    const s16x8* bp_ = bp + (KK) * 256; \
    GLF(pb0[S], bp_); GLF(pb1[S], bp_ + 64); \
    GLF(pb2[S], bp_ + 128); GLF(pb3[S], bp_ + 192); }

  f32x4 acc[4];
#pragma unroll
  for (int ct = 0; ct < 4; ++ct) acc[ct] = (f32x4){0.f, 0.f, 0.f, 0.f};

  ISSUE(0, 0);
  ISSUE(1, 1);
#pragma unroll
  for (int k = 0; k < KH; ++k) {
    if (k + 2 < KH) {
      ISSUE(k + 2, (k + 2) % 3);
      asm volatile("s_waitcnt vmcnt(12)" ::: "memory");  // slot k landed
    } else if (k + 2 == KH) {
      asm volatile("s_waitcnt vmcnt(6)" ::: "memory");
    } else {
      asm volatile("s_waitcnt vmcnt(0)" ::: "memory");
    }
    __builtin_amdgcn_sched_barrier(0);
    int s = k % 3;                          // compile-time after unroll
    s16x8 af;
    af[0]=f2bf(pa0[s][0]); af[1]=f2bf(pa0[s][1]);
    af[2]=f2bf(pa0[s][2]); af[3]=f2bf(pa0[s][3]);
    af[4]=f2bf(pa1[s][0]); af[5]=f2bf(pa1[s][1]);
    af[6]=f2bf(pa1[s][2]); af[7]=f2bf(pa1[s][3]);
    acc[0] = __builtin_amdgcn_mfma_f32_16x16x32_bf16(af, pb0[s], acc[0], 0, 0, 0);
    acc[1] = __builtin_amdgcn_mfma_f32_16x16x32_bf16(af, pb1[s], acc[1], 0, 0, 0);
    acc[2] = __builtin_amdgcn_mfma_f32_16x16x32_bf16(af, pb2[s], acc[2], 0, 0, 0);
    acc[3] = __builtin_amdgcn_mfma_f32_16x16x32_bf16(af, pb3[s], acc[3], 0, 0, 0);
  }
#undef ISSUE
#undef GLF

  // ---- K-split reduce: ks=1 dumps partials, ks=0 combines + writes ----
  float* rb = red + rg * 1024;              // [64][16] per row-group
  if (ks == 1) {
#pragma unroll
    for (int ct = 0; ct < 4; ++ct)
      *(f32x4*)(rb + lane * 16 + ct * 4) = acc[ct];
  }
  __syncthreads();
  if (ks == 0) {
#pragma unroll
    for (int ct = 0; ct < 4; ++ct) {
      f32x4 o = *(const f32x4*)(rb + lane * 16 + ct * 4);
      int col = ct * 16 + rl;
      float bv = (col < 50) ? bias[col] : 0.f;
#pragma unroll
      for (int r = 0; r < 4; ++r) {
        int grow = row0 + q * 4 + r;         // D row = quad*4+reg (m89)
        float v = fmaxf(acc[ct][r] + o[r] + bv, 0.f);
        out[(long)grow * 64 + col] = (col < 50) ? v : 0.f;
      }
    }
  }
}

// MLP tail body: one block per batch row; sums the 23 per-job GEMM slices.
__device__ __forceinline__ void mix_body(
    int r, const float* __restrict__ pre,
    const float* __restrict__ b_gt, const float* __restrict__ b_gi,
    const float* __restrict__ W_m1, const float* __restrict__ b_m1,
    const float* __restrict__ W_m2, const float* __restrict__ b_m2,
    float* __restrict__ mix, float* smem) {
  float* sm = smem;            // [200]
  float* sh = smem + 200;      // [100]
  int t = threadIdx.x;
  if (t < 200) {
    float s1 = b_gt[t], s2 = b_gi[t];
#pragma unroll
    for (int j = 0; j < 7; ++j)  s1 += pre[(long)j * 25600 + r * 200 + t];
#pragma unroll
    for (int j = 7; j < 23; ++j) s2 += pre[(long)j * 25600 + r * 200 + t];
    sm[t] = fmaxf(s1, 0.f) + fmaxf(s2, 0.f);
  }
  __syncthreads();
  if (t < 100) {
    float a = b_m1[t];
#pragma unroll 4
    for (int k = 0; k < 200; ++k) a += sm[k] * W_m1[k * 100 + t];
    sh[t] = fmaxf(a, 0.f);
  }
  __syncthreads();
  if (t < 2) {
    float a = b_m2[t];
    for (int k = 0; k < 100; ++k) a += sh[k] * W_m2[k * 2 + t];
    mix[r * 2 + t] = a;
  }
}

// Grid order: img proj [0,144) first (longest: 32 steps/wave), txt proj
// [144,1168), mix [1168,1296) last (tiny).
__global__ __launch_bounds__(256)
__attribute__((amdgpu_waves_per_eu(2, 4)))
void k_pm(
    const float* __restrict__ txt_region, const short* __restrict__ frt,
    const float* __restrict__ b_rt, float* __restrict__ tr,
    const float* __restrict__ img_region, const short* __restrict__ fri,
    const float* __restrict__ b_ri, float* __restrict__ ir,
    const float* __restrict__ pre,
    const float* __restrict__ b_gt, const float* __restrict__ b_gi,
    const float* __restrict__ W_m1, const float* __restrict__ b_m1,
    const float* __restrict__ W_m2, const float* __restrict__ b_m2,
    float* __restrict__ mix) {
  __shared__ __align__(16) float red[2048];   // 8 KB reduce / mix scratch
  int bid = blockIdx.x;
  if (bid < 144)       proj_body<64>(img_region, fri, b_ri, ir, bid, red);
  else if (bid < 1168) proj_body<24>(txt_region, frt, b_rt, tr, bid - 144, red);
  else                 mix_body(bid - 1168, pre, b_gt, b_gi, W_m1, b_m1, W_m2, b_m2, mix, red);
}

// ---------------------------------------------------------------------------
// k_sxx: XX Sinkhorn, 512 threads (8 waves). Column j = tid&255, i-groups
// stride-2 interleaved across kk = tid>>8 (balanced for any n), trip count
// tmax = ceil(n/16), partial unroll 4 -> 4 independent ds_read_b128 in
// flight. CT swizzle mask (j&31): all 32 16B slots/row distinct across a
// half-wave -> 2-way aliasing only. Reads past n are safe: CT fully
// written & finite; alpha[i>=n] = -65504 forever, never wins the max.
// ---------------------------------------------------------------------------
__global__ __launch_bounds__(512) void k_sxx(
    const float* __restrict__ tr, const int* __restrict__ amask,
    float* __restrict__ Sxx) {
  __shared__ __align__(16) char smem[163840];
  char*  CT    = smem;                       // f16 CT[256][512B] XOR-swz
  float* norms = (float*)smem;               // temp, inside CT region
  short* Xf    = (short*)(smem + 131072);    // 32 KB, dead after MFMA phase
  float*     sPm = (float*)(smem + 131072);  // [2][256] aliases Xf
  float*     sF  = (float*)(smem + 133120);
  float*     sG  = (float*)(smem + 134144);
  _Float16*  sAh = (_Float16*)(smem + 135168);
  int b = blockIdx.x, tid = threadIdx.x;
  int lane = tid & 63, wv = tid >> 6;
  int q = lane >> 4, rl = lane & 15;

  // ---- n: per-wave reduce ----
  int c = 0;
#pragma unroll
  for (int i = 0; i < 4; ++i) c += amask[b * 256 + i * 64 + lane];
#pragma unroll
  for (int o = 1; o < 64; o <<= 1) c += __shfl_xor(c, o);
  int n = __builtin_amdgcn_readfirstlane(c);

  // ---- stage Xf (bf16 MFMA frags of X) ----
  const float* Xg = tr + (long)b * 256 * 64;
  for (int slot = tid; slot < 2048; slot += 512) {
    int t = slot >> 7, k32 = (slot >> 6) & 1, l = slot & 63;
    int row = t * 16 + (l & 15), k0 = k32 * 32 + (l >> 4) * 8;
    const float* src = Xg + row * 64 + k0;
    f32x4 a0 = *(const f32x4*)src, a1 = *(const f32x4*)(src + 4);
    s16x8 p;
    p[0]=f2bf(a0[0]); p[1]=f2bf(a0[1]); p[2]=f2bf(a0[2]); p[3]=f2bf(a0[3]);
    p[4]=f2bf(a1[0]); p[5]=f2bf(a1[1]); p[6]=f2bf(a1[2]); p[7]=f2bf(a1[3]);
    *(s16x8*)(Xf + slot * 8) = p;
  }
  __syncthreads();

  // ---- phase 1: diag tiles -> norms (in CT region, not yet written) ----
#pragma unroll
  for (int si = 0; si < 2; ++si) {
    int st = wv * 2 + si;
    s16x8 a0 = *(const s16x8*)(Xf + ((st * 2 + 0) * 64 + lane) * 8);
    s16x8 a1 = *(const s16x8*)(Xf + ((st * 2 + 1) * 64 + lane) * 8);
    f32x4 d = (f32x4){0.f, 0.f, 0.f, 0.f};
    d = __builtin_amdgcn_mfma_f32_16x16x32_bf16(a0, a0, d, 0, 0, 0);
    d = __builtin_amdgcn_mfma_f32_16x16x32_bf16(a1, a1, d, 0, 0, 0);
#pragma unroll
    for (int r = 0; r < 4; ++r)
      if (rl == q * 4 + r) norms[st * 16 + q * 4 + r] = d[r];
  }
  __syncthreads();

  // preload ALL norms this thread needs into registers, then barrier so
  // phase-2 CT writes can safely clobber the norms slice.
  float nj[16];
#pragma unroll
  for (int ct = 0; ct < 16; ++ct) nj[ct] = norms[ct * 16 + rl];
  float ni[2][4];
#pragma unroll
  for (int si = 0; si < 2; ++si) {
    int base = (wv * 2 + si) * 16 + q * 4;
#pragma unroll
    for (int r = 0; r < 4; ++r) ni[si][r] = norms[base + r];
  }
  __syncthreads();

  // ---- phase 2: full tiles per strip; write CT[j][i] f16 swizzled ----
#pragma unroll
  for (int si = 0; si < 2; ++si) {
    int st = wv * 2 + si;
    int i0w = st * 16 + q * 4;
    s16x8 a0 = *(const s16x8*)(Xf + ((st * 2 + 0) * 64 + lane) * 8);
    s16x8 a1 = *(const s16x8*)(Xf + ((st * 2 + 1) * 64 + lane) * 8);
    f32x4 acc[16];
#pragma unroll
    for (int ct = 0; ct < 16; ++ct) acc[ct] = (f32x4){0.f, 0.f, 0.f, 0.f};
#pragma unroll
    for (int ct = 0; ct < 16; ++ct) {
      s16x8 b0 = *(const s16x8*)(Xf + ((ct * 2 + 0) * 64 + lane) * 8);
      s16x8 b1 = *(const s16x8*)(Xf + ((ct * 2 + 1) * 64 + lane) * 8);
      acc[ct] = __builtin_amdgcn_mfma_f32_16x16x32_bf16(a0, b0, acc[ct], 0, 0, 0);
      acc[ct] = __builtin_amdgcn_mfma_f32_16x16x32_bf16(a1, b1, acc[ct], 0, 0, 0);
    }
#pragma unroll
    for (int ct = 0; ct < 16; ++ct) {
      int j = ct * 16 + rl;
      float njv = nj[ct];
      float v0 = (acc[ct][0] - 0.5f * (ni[si][0] + njv)) * INV_EPS_LN2;
      float v1 = (acc[ct][1] - 0.5f * (ni[si][1] + njv)) * INV_EPS_LN2;
      float v2 = (acc[ct][2] - 0.5f * (ni[si][2] + njv)) * INV_EPS_LN2;
      float v3 = (acc[ct][3] - 0.5f * (ni[si][3] + njv)) * INV_EPS_LN2;
      char* p = CT + (((j << 9) + (i0w << 1)) ^ ((j & 31) << 4));
      *(unsigned*)(p)     = (unsigned)f2h(v0) | ((unsigned)f2h(v1) << 16);
      *(unsigned*)(p + 4) = (unsigned)f2h(v2) | ((unsigned)f2h(v3) << 16);
    }
  }
  __syncthreads();                           // Xf dead; CT complete

  // ---- init loop state (aliases Xf region) ----
  float log2n = log2f((float)n);
  if (tid < 256) {
    sF[tid] = 0.f; sG[tid] = 0.f;
    sAh[tid] = (tid < n) ? (_Float16)(-log2n) : (_Float16)(-65504.f);
  }
  __syncthreads();

  // ---- 40 max-plus half-steps: column j, stride-2 kk split, unroll 4 ----
  int kk = tid >> 8, j = tid & 255;
  unsigned base = (unsigned)(j << 9);
  unsigned sw   = (unsigned)((j & 31) << 4);
  int tmax = (n + 15) >> 4;                  // ceil(n/16); s = 2t+kk <= 31
  const char* aB = (const char*)sAh;
  for (int h = 0; h < 40; ++h) {
    unsigned mm = 0xFBFFFBFFu;               // {-65504, -65504}
#pragma unroll 4
    for (int t = 0; t < tmax; ++t) {
      int s = 2 * t + kk;
      u32x4 v  = *(const u32x4*)(CT + ((base + (unsigned)(s << 4)) ^ sw));
      u32x4 av = *(const u32x4*)(aB + s * 16);     // broadcast (uniform addr)
      unsigned t0, t1, t2, t3;
      asm("v_pk_add_f16 %0, %1, %2" : "=v"(t0) : "v"(v[0]), "v"(av[0]));
      asm("v_pk_add_f16 %0, %1, %2" : "=v"(t1) : "v"(v[1]), "v"(av[1]));
      asm("v_pk_add_f16 %0, %1, %2" : "=v"(t2) : "v"(v[2]), "v"(av[2]));
      asm("v_pk_add_f16 %0, %1, %2" : "=v"(t3) : "v"(v[3]), "v"(av[3]));
      asm("v_pk_max_f16 %0, %0, %1" : "+v"(mm) : "v"(t0));
      asm("v_pk_max_f16 %0, %0, %1" : "+v"(mm) : "v"(t1));
      asm("v_pk_max_f16 %0, %0, %1" : "+v"(mm) : "v"(t2));
      asm("v_pk_max_f16 %0, %0, %1" : "+v"(mm) : "v"(t3));
    }
    sPm[kk * 256 + j] = fmaxf(h2f((unsigned short)(mm & 0xFFFFu)),
                              h2f((unsigned short)(mm >> 16)));
    __syncthreads();
    if (tid < 256) {
      float m2 = fmaxf(sPm[tid], sPm[256 + tid]);
      if (tid < n) {
        ((h & 1) ? sF : sG)[tid] = -EPS_LN2 * m2;
        sAh[tid] = (_Float16)(-log2n - m2);
      }
    }
    __syncthreads();
  }
  if (tid < 64) {
    float a = 0.f;
    for (int i = tid; i < n; i += 64) a += sF[i] + sG[i];
#pragma unroll
    for (int o = 1; o < 64; o <<= 1) a += __shfl_xor(a, o);
    if (tid == 0) Sxx[b] = a / n;
  }
}

// ---------------------------------------------------------------------------
// k_sxy: XY (blocks [0,128)) and YY (blocks [128,256)) Sinkhorn, unchanged.
// ---------------------------------------------------------------------------
#define SK_SMEM 50736

__global__ __launch_bounds__(1024) void k_sxy(
    const float* __restrict__ tr, const float* __restrict__ ir,
    const int* __restrict__ amask,
    float* __restrict__ Sxy, float* __restrict__ Syy) {
  __shared__ __align__(16) char smem[SK_SMEM];
  int role = blockIdx.x >> 7;
  int b    = blockIdx.x & 127;
  int tid  = threadIdx.x;

  if (role == 0) {
    // ====================== XY ======================
    float* Ys  = (float*)smem;                    // [36][64]
    float* Cs  = (float*)(smem + 9216);           // [256][37]
    float* nx  = (float*)(smem + 47104);          // [256]
    float* ny  = (float*)(smem + 48128);          // [36]
    float* sA  = (float*)(smem + 48288);          // padded alpha [272]
    float* sB  = (float*)(smem + 49376);          // beta [36]
    float* sF  = (float*)(smem + 49536);          // [256]
    float* sG  = (float*)(smem + 50560);          // [36]
    int*   nsh = (int*)  (smem + 50720);
    if (tid < 64) {
      int c = 0;
      for (int i = tid; i < 256; i += 64) c += amask[b * 256 + i];
#pragma unroll
      for (int o = 1; o < 64; o <<= 1) c += __shfl_xor(c, o);
      if (tid == 0) *nsh = c;
    }
    const float* Xg = tr + (long)b * 256 * 64;
    const float* Yg = ir + (long)b * 36 * 64;
    for (int idx = tid; idx < 576; idx += 1024) {
      int row = idx >> 4, q4 = idx & 15;
      *(f32x4*)(Ys + row * 64 + q4 * 4) = *(const f32x4*)(Yg + row * 64 + q4 * 4);
    }
    __syncthreads();
    int n = *nsh;
    if (tid < 256) {
      float a = 0.f;
#pragma unroll
      for (int q4 = 0; q4 < 13; ++q4) {
        f32x4 v = *(const f32x4*)(Xg + tid * 64 + q4 * 4);
        a += v[0]*v[0] + v[1]*v[1] + v[2]*v[2] + v[3]*v[3];
      }
      nx[tid] = a;
    } else if (tid < 292) {
      int jj = tid - 256; float a = 0.f;
#pragma unroll
      for (int q4 = 0; q4 < 13; ++q4) {
        f32x4 v = *(const f32x4*)(Ys + jj * 64 + q4 * 4);
        a += v[0]*v[0] + v[1]*v[1] + v[2]*v[2] + v[3]*v[3];
      }
      ny[jj] = a;
    }
    __syncthreads();
    if (tid < 1008) {
      int ii = tid / 36, jj = tid - ii * 36;
      f32x4 yr[13];
#pragma unroll
      for (int q4 = 0; q4 < 13; ++q4) yr[q4] = *(const f32x4*)(Ys + jj * 64 + q4 * 4);
      float nyj = ny[jj];
      for (int i = ii; i < 256; i += 28) {
        float d = 0.f;
#pragma unroll
        for (int q4 = 0; q4 < 13; ++q4) {
          f32x4 xv = *(const f32x4*)(Xg + i * 64 + q4 * 4);
          d += xv[0]*yr[q4][0] + xv[1]*yr[q4][1] + xv[2]*yr[q4][2] + xv[3]*yr[q4][3];
        }
        Cs[i * 37 + jj] = (d - 0.5f * (nx[i] + nyj)) * INV_EPS_LN2;
      }
    }
    __syncthreads();
    int jg = tid >> 4, kg = tid & 15;             // g-role: column jg, slice kg
    float Cg[16];
    if (jg < 36) {
#pragma unroll
      for (int t = 0; t < 16; ++t) Cg[t] = Cs[(kg * 16 + t) * 37 + jg];
    }
    int fi = tid >> 2, kf = tid & 3;              // f-role: row fi, slice kf
    float Cf[9];
#pragma unroll
    for (int t = 0; t < 9; ++t) {
      int jj2 = kf * 9 + t;
      Cf[t] = (jj2 < 36) ? Cs[fi * 37 + jj2] : 0.f;
    }
    float log2n = log2f((float)n);
    if (tid < 256) { sF[tid] = 0.f; sA[tid + (tid >> 4)] = -log2n; }
    __syncthreads();
    const float* agp = sA + kg * 17;
    int gend = n - kg * 16; if (gend > 16) gend = 16;
    for (int it = 0; it < 20; ++it) {
      float gm = -1e30f;
      if (jg < 36) {
#pragma unroll
        for (int t = 0; t < 16; ++t)
          if (t < gend) gm = fmaxf(gm, agp[t] + Cg[t]);
        gm = fmaxf(gm, __shfl_xor(gm, 1)); gm = fmaxf(gm, __shfl_xor(gm, 2));
        gm = fmaxf(gm, __shfl_xor(gm, 4)); gm = fmaxf(gm, __shfl_xor(gm, 8));
      }
      __syncthreads();
      if (jg < 36 && kg == 0) {
        sG[jg] = -EPS_LN2 * gm;
        sB[jg] = -LOG2_36 - gm;
      }
      __syncthreads();
      float fm = -1e30f;
#pragma unroll
      for (int t = 0; t < 9; ++t) {
        int jj2 = kf * 9 + t;
        if (jj2 < 36) fm = fmaxf(fm, sB[jj2] + Cf[t]);
      }
      fm = fmaxf(fm, __shfl_xor(fm, 1)); fm = fmaxf(fm, __shfl_xor(fm, 2));
      __syncthreads();
      if (kf == 0 && fi < n) {
        sF[fi] = -EPS_LN2 * fm;
        sA[fi + (fi >> 4)] = -log2n - fm;
      }
      __syncthreads();
    }
    if (tid < 64) {
      float a = 0.f;
      for (int i = tid; i < n; i += 64) a += sF[i];
      float g = (tid < 36) ? sG[tid] : 0.f;
#pragma unroll
      for (int o = 1; o < 64; o <<= 1) { a += __shfl_xor(a, o); g += __shfl_xor(g, o); }
      if (tid == 0) Sxy[b] = a / n + g / 36.f;
    }
  } else {
    // ====================== YY ======================
    float* Ys = (float*)smem;                     // [36][64]
    float* Cs = (float*)(smem + 9216);            // [36][37]
    float* ny = (float*)(smem + 48128);
    float* sA = (float*)(smem + 48288);           // [36]
    float* sF = (float*)(smem + 49536);
    float* sG = (float*)(smem + 50560);
    const float* Yg = ir + (long)b * 36 * 64;
    for (int idx = tid; idx < 576; idx += 1024) {
      int row = idx >> 4, q4 = idx & 15;
      *(f32x4*)(Ys + row * 64 + q4 * 4) = *(const f32x4*)(Yg + row * 64 + q4 * 4);
    }
    __syncthreads();
    if (tid < 36) {
      float a = 0.f;
#pragma unroll
      for (int q4 = 0; q4 < 13; ++q4) {
        f32x4 v = *(const f32x4*)(Ys + tid * 64 + q4 * 4);
        a += v[0]*v[0] + v[1]*v[1] + v[2]*v[2] + v[3]*v[3];
      }
      ny[tid] = a;
    }
    __syncthreads();
    if (tid < 1008) {
      int ii = tid / 36, jj = tid - ii * 36;
      f32x4 yr[13];
#pragma unroll
      for (int q4 = 0; q4 < 13; ++q4) yr[q4] = *(const f32x4*)(Ys + jj * 64 + q4 * 4);
      float nyj = ny[jj];
      for (int i = ii; i < 36; i += 28) {
        float d = 0.f;
#pragma unroll
        for (int q4 = 0; q4 < 13; ++q4) {
          f32x4 xv = *(const f32x4*)(Ys + i * 64 + q4 * 4);
          d += xv[0]*yr[q4][0] + xv[1]*yr[q4][1] + xv[2]*yr[q4][2] + xv[3]*yr[q4][3];
        }
        Cs[i * 37 + jj] = (d - 0.5f * (ny[i] + nyj)) * INV_EPS_LN2;
      }
    }
    __syncthreads();
    int j = tid >> 2, kk = tid & 3;
    float Creg[9];
    if (j < 36) {
#pragma unroll
      for (int t = 0; t < 9; ++t) {
        int i2 = kk * 9 + t;
        Creg[t] = (i2 < 36) ? Cs[i2 * 37 + j] : 0.f;
      }
    }
    if (tid < 36) { sF[tid] = 0.f; sA[tid] = -LOG2_36; }
    __syncthreads();
    for (int h = 0; h < 40; ++h) {
      float m = -1e30f;
      if (j < 36) {
#pragma unroll
        for (int t = 0; t < 9; ++t) {
          int i2 = kk * 9 + t;
          if (i2 < 36) m = fmaxf(m, sA[i2] + Creg[t]);
        }
        m = fmaxf(m, __shfl_xor(m, 1)); m = fmaxf(m, __shfl_xor(m, 2));
      }
      __syncthreads();
      if (j < 36 && kk == 0) {
        ((h & 1) ? sF : sG)[j] = -EPS_LN2 * m;
        sA[j] = -LOG2_36 - m;
      }
      __syncthreads();
    }
    if (tid < 64) {
      float a = (tid < 36) ? sF[tid] + sG[tid] : 0.f;
#pragma unroll
      for (int o = 1; o < 64; o <<= 1) a += __shfl_xor(a, o);
      if (tid == 0) Syy[b] = a / 36.f;
    }
  }
}

// ---------------------------------------------------------------------------
// Final combine: w_dis -> w_pred, max with mix_pred, 2-way softmax.
// ---------------------------------------------------------------------------
__global__ void k_final(const float* __restrict__ mix, const float* __restrict__ sxy,
                        const float* __restrict__ sxx, const float* __restrict__ syy,
                        float* __restrict__ out) {
  int b = blockIdx.x * 64 + threadIdx.x;
  if (b < 128) {
    float w  = sxy[b] - 0.5f * (sxx[b] + syy[b]);
    float x0 = fmaxf(mix[b * 2 + 0], 1.0f - 0.01f * w);
    float x1 = fmaxf(mix[b * 2 + 1], 0.01f * w);
    float mx = fmaxf(x0, x1);
    float e0 = expf(x0 - mx), e1 = expf(x1 - mx);
    float inv = 1.f / (e0 + e1);
    out[b * 2 + 0] = e0 * inv;
    out[b * 2 + 1] = e1 * inv;
  }
}

// ---------------------------------------------------------------------------
extern "C" void kernel_launch(void* const* d_in, const int* in_sizes, int n_in,
                              void* d_out, int out_size, void* d_ws, size_t ws_size,
                              hipStream_t stream) {
  const float* txt_global = (const float*)d_in[0];
  const float* txt_region = (const float*)d_in[1];
  const float* img_global = (const float*)d_in[2];
  const float* img_region = (const float*)d_in[3];
  const float* social     = (const float*)d_in[4];
  const int*   attn_mask  = (const int*)  d_in[5];
  const float* W_stat = (const float*)d_in[6];  const float* b_stat = (const float*)d_in[7];
  const float* W_gt   = (const float*)d_in[8];  const float* b_gt   = (const float*)d_in[9];
  const float* W_gi   = (const float*)d_in[10]; const float* b_gi   = (const float*)d_in[11];
  const float* W_rt   = (const float*)d_in[12]; const float* b_rt   = (const float*)d_in[13];
  const float* W_ri   = (const float*)d_in[14]; const float* b_ri   = (const float*)d_in[15];
  const float* W_m1   = (const float*)d_in[16]; const float* b_m1   = (const float*)d_in[17];
  const float* W_m2   = (const float*)d_in[18]; const float* b_m2   = (const float*)d_in[19];

  float* ws = (float*)d_ws;
  float* ws_mix = ws;                    // 256
  float* ws_sxy = ws + 256;              // 128
  float* ws_sxx = ws + 384;              // 128
  float* ws_syy = ws + 512;              // 128
  short* ws_frt = (short*)(ws + 1024);   // 49152 shorts -> ends float 25600
  short* ws_fri = (short*)(ws + 25600);  // 131072 shorts -> ends float 91136
  float* ws_tr  = ws + 131072;           // [32768][64]
  float* ws_ir  = ws + 2228224;          // [4608][64]
  float* ws_pre = ws + 2523136;          // [23][128][200]

  k_prep<<<456, 256, 0, stream>>>(W_rt, W_ri, ws_frt, ws_fri,
                                  txt_global, img_global, social,
                                  W_stat, b_stat, W_gt, W_gi, ws_pre);
  k_pm<<<1296, 256, 0, stream>>>(txt_region, ws_frt, b_rt, ws_tr,
                                 img_region, ws_fri, b_ri, ws_ir,
                                 ws_pre, b_gt, b_gi,
                                 W_m1, b_m1, W_m2, b_m2, ws_mix);
  k_sxx<<<128, 512, 0, stream>>>(ws_tr, attn_mask, ws_sxx);
  k_sxy<<<256, 1024, 0, stream>>>(ws_tr, ws_ir, attn_mask, ws_sxy, ws_syy);
  k_final<<<2, 64, 0, stream>>>(ws_mix, ws_sxy, ws_sxx, ws_syy, (float*)d_out);
}